// Round 13
// baseline (377.940 us; speedup 1.0000x reference)
//
#include <hip/hip_runtime.h>
#include <math.h>

#define DEV __device__ __forceinline__

typedef float  f4v  __attribute__((ext_vector_type(4)));
typedef __bf16 b8v  __attribute__((ext_vector_type(8)));
typedef short  s8v  __attribute__((ext_vector_type(8)));

DEV short f2b(float f){ __bf16 h = (__bf16)f; return __builtin_bit_cast(short, h); }
DEV float b2f(short s){ __bf16 h = __builtin_bit_cast(__bf16, s); return (float)h; }

DEV void gload16(const void* g, void* l){
  __builtin_amdgcn_global_load_lds((const __attribute__((address_space(1))) void*)g,
                                   (__attribute__((address_space(3))) void*)l, 16, 0, 0);
}

DEV b8v ldsf(const short* p){ return __builtin_bit_cast(b8v, *(const s8v*)p); }
DEV b8v gldf(const short* p){ return __builtin_bit_cast(b8v, *(const s8v*)p); }

DEV f4v mfma16(b8v a, b8v b, f4v c){ return __builtin_amdgcn_mfma_f32_16x16x32_bf16(a, b, c, 0, 0, 0); }

// LDS-only barrier: does NOT drain vmcnt (m201 pattern).
DEV void lds_barrier(){
  asm volatile("s_waitcnt lgkmcnt(0)" ::: "memory");
  __builtin_amdgcn_s_barrier();
}

// ---------------- prep: ln(x) -> xn  AND  f32->bf16 converts, one launch ----------------
__global__ __launch_bounds__(256) void prep_kernel(const float* __restrict__ x, const float* __restrict__ ln1g,
                                                   const float* __restrict__ ln1b, short* __restrict__ xn,
                                                   const float* __restrict__ s0, const float* __restrict__ s1,
                                                   const float* __restrict__ s2, const float* __restrict__ s3,
                                                   const float* __restrict__ s4,
                                                   short* __restrict__ d0, short* __restrict__ d1,
                                                   short* __restrict__ d2, short* __restrict__ d3,
                                                   short* __restrict__ d4){
  int bid = blockIdx.x, tid = threadIdx.x;
  if (bid < 5120){
    int i = bid*256 + tid;   // 5 * 262144 float4s
    int buf = i >> 18, j = i & 262143;
    const float* s = (buf==0)?s0:(buf==1)?s1:(buf==2)?s2:(buf==3)?s3:s4;
    short*       d = (buf==0)?d0:(buf==1)?d1:(buf==2)?d2:(buf==3)?d3:d4;
    float4 v = ((const float4*)s)[j];
    ((short4*)d)[j] = make_short4(f2b(v.x), f2b(v.y), f2b(v.z), f2b(v.w));
    return;
  }
  int row = bid - 5120;
  const float4 v = ((const float4*)(x + (size_t)row*1024))[tid];
  float s = v.x + v.y + v.z + v.w;
  #pragma unroll
  for (int off=1; off<64; off<<=1) s += __shfl_xor(s, off);
  __shared__ float red[4];
  if ((tid&63)==0) red[tid>>6] = s;
  __syncthreads();
  float mu = (red[0]+red[1]+red[2]+red[3]) * (1.0f/1024.0f);
  float e0=v.x-mu, e1=v.y-mu, e2=v.z-mu, e3=v.w-mu;
  float q = e0*e0 + e1*e1 + e2*e2 + e3*e3;
  #pragma unroll
  for (int off=1; off<64; off<<=1) q += __shfl_xor(q, off);
  __syncthreads();
  if ((tid&63)==0) red[tid>>6] = q;
  __syncthreads();
  float rs = rsqrtf((red[0]+red[1]+red[2]+red[3]) * (1.0f/1024.0f) + 1e-5f);
  float4 g4 = ((const float4*)ln1g)[tid];
  float4 b4 = ((const float4*)ln1b)[tid];
  short4 o = make_short4(f2b(e0*rs*g4.x + b4.x), f2b(e1*rs*g4.y + b4.y),
                         f2b(e2*rs*g4.z + b4.z), f2b(e3*rs*g4.w + b4.w));
  ((short4*)(xn + (size_t)row*1024))[tid] = o;
}

// ---------------- LayerNorm fused with 32-slice sum reduce (bf16 O-partials) ----------------
__global__ __launch_bounds__(256) void ln_reduce_kernel(const short* __restrict__ opart, const float* __restrict__ gg,
                                                        const float* __restrict__ bb, short* __restrict__ out){
  int row = blockIdx.x, tid = threadIdx.x;
  float a0=0.f, a1=0.f, a2=0.f, a3=0.f;
  #pragma unroll
  for (int sc=0; sc<32; ++sc){
    short4 t = ((const short4*)(opart + ((size_t)sc*1024 + row)*1024))[tid];
    a0 += b2f(t.x); a1 += b2f(t.y); a2 += b2f(t.z); a3 += b2f(t.w);
  }
  float s = a0 + a1 + a2 + a3;
  #pragma unroll
  for (int off=1; off<64; off<<=1) s += __shfl_xor(s, off);
  __shared__ float red[4];
  if ((tid&63)==0) red[tid>>6] = s;
  __syncthreads();
  float mu = (red[0]+red[1]+red[2]+red[3]) * (1.0f/1024.0f);
  float d0=a0-mu, d1=a1-mu, d2=a2-mu, d3=a3-mu;
  float q = d0*d0 + d1*d1 + d2*d2 + d3*d3;
  #pragma unroll
  for (int off=1; off<64; off<<=1) q += __shfl_xor(q, off);
  __syncthreads();
  if ((tid&63)==0) red[tid>>6] = q;
  __syncthreads();
  float rs = rsqrtf((red[0]+red[1]+red[2]+red[3]) * (1.0f/1024.0f) + 1e-5f);
  float4 g4 = ((const float4*)gg)[tid];
  float4 b4 = ((const float4*)bb)[tid];
  short4 o = make_short4(f2b(d0*rs*g4.x + b4.x), f2b(d1*rs*g4.y + b4.y),
                         f2b(d2*rs*g4.z + b4.z), f2b(d3*rs*g4.w + b4.w));
  ((short4*)(out + (size_t)row*1024))[tid] = o;
}

// ---------------- small GEMM (M,N ~1024): 64x64 tile, BK=64, counted-vmcnt 2-phase ----------------
template<int OUTF32>
__global__ __launch_bounds__(256) void gemm_small(const short* __restrict__ A, const short* __restrict__ B,
                                                  void* __restrict__ C, int M, int N, int K){
  __shared__ short sA[2][64*64];
  __shared__ short sB[2][64*64];
  int tid=threadIdx.x, lane=tid&63, wv=tid>>6, g=lane>>4, r=lane&15;
  int wr=wv>>1, wc=wv&1;
  int m0=blockIdx.x*64, n0=blockIdx.y*64;
  f4v z = {0.f,0.f,0.f,0.f};
  f4v acc[2][2];
  #pragma unroll
  for (int i=0;i<2;++i){
    #pragma unroll
    for (int j=0;j<2;++j) acc[i][j]=z;
  }
  auto stage = [&](int buf, int kt){   // exactly 4 VMEM ops per thread
    #pragma unroll
    for (int i=0;i<2;++i){
      int idx = i*256 + tid;
      int row = idx>>3, cbs = (idx&7)^(row&7);
      gload16(A + (size_t)(m0+row)*K + kt*64 + cbs*8, &sA[buf][(i*256+wv*64)*8]);
      gload16(B + (size_t)(n0+row)*K + kt*64 + cbs*8, &sB[buf][(i*256+wv*64)*8]);
    }
  };
  int nkt = K >> 6;
  stage(0, 0);
  for (int kt=0; kt<nkt; ++kt){
    int cur = kt & 1;
    if (kt+1 < nkt){
      stage(cur^1, kt+1);
      asm volatile("s_waitcnt vmcnt(4)" ::: "memory");  // cur tile landed; prefetch in flight
    } else {
      asm volatile("s_waitcnt vmcnt(0)" ::: "memory");
    }
    __builtin_amdgcn_s_barrier();
    b8v af[2][2], bf[2][2];
    #pragma unroll
    for (int mf=0;mf<2;++mf){
      #pragma unroll
      for (int ks=0;ks<2;++ks){
        int ra = wr*32 + mf*16 + r;
        int rb = wc*32 + mf*16 + r;
        af[mf][ks] = ldsf(&sA[cur][ra*64 + (((ks*4+g)^(ra&7))*8)]);
        bf[mf][ks] = ldsf(&sB[cur][rb*64 + (((ks*4+g)^(rb&7))*8)]);
      }
    }
    #pragma unroll
    for (int mf=0;mf<2;++mf){
      #pragma unroll
      for (int nf=0;nf<2;++nf){
        acc[mf][nf] = mfma16(af[mf][0], bf[nf][0], acc[mf][nf]);
        acc[mf][nf] = mfma16(af[mf][1], bf[nf][1], acc[mf][nf]);
      }
    }
    asm volatile("s_waitcnt lgkmcnt(0)" ::: "memory");  // own LDS reads done
    __builtin_amdgcn_s_barrier();                       // everyone done -> safe to re-stage
  }
  #pragma unroll
  for (int mf=0;mf<2;++mf){
    #pragma unroll
    for (int nf=0;nf<2;++nf){
      #pragma unroll
      for (int j=0;j<4;++j){
        int m = m0 + wr*32 + mf*16 + g*4 + j;
        int n = n0 + wc*32 + nf*16 + r;
        if (OUTF32) ((float*)C)[(size_t)m*N + n] = acc[mf][nf][j];
        else        ((short*)C)[(size_t)m*N + n] = f2b(acc[mf][nf][j]);
      }
    }
  }
}

// ======== fused K+V 8-phase GEMM: BM=256, BN=128 per output, BK=64, counted vmcnt ========
__global__ __launch_bounds__(512,1) void gemm_dual8(const short* __restrict__ A, const short* __restrict__ B0,
                                                    const short* __restrict__ B1, short* __restrict__ C0,
                                                    short* __restrict__ vt){
  __shared__ short sA[2][256*64];   // 64 KB  (halves: rows 0-127 / 128-255 of lds-rows)
  __shared__ short sBK[2][128*64];  // 32 KB
  __shared__ short sBV[2][128*64];  // 32 KB
  int tid=threadIdx.x, lane=tid&63, wv=tid>>6, g=lane>>4, r=lane&15;
  int wr=wv>>2, wc=wv&3;            // 2M x 4N waves; wave tile 128m x 32n per output
  int m0 = blockIdx.x*256, n0 = blockIdx.y*128;
  f4v z = {0.f,0.f,0.f,0.f};
  f4v ac0[8][2], ac1[8][2];
  #pragma unroll
  for (int i=0;i<8;++i){
    #pragma unroll
    for (int j=0;j<2;++j){ ac0[i][j]=z; ac1[i][j]=z; }
  }
  auto stageA = [&](int buf, int kt, int h){
    #pragma unroll
    for (int ii=0; ii<2; ++ii){
      int idx = ii*512 + tid;                       // 0..1023 within half
      int rl = idx>>3, cs = (idx&7)^(rl&7);
      int rowA = (((rl>>6)&1)<<7) | (h<<6) | (rl&63);
      gload16(A + (size_t)(m0+rowA)*1024 + kt*64 + cs*8,
              &sA[buf][(h*1024 + ii*512 + wv*64)*8]);
    }
  };
  auto stageBK = [&](int buf, int kt){
    #pragma unroll
    for (int ii=0; ii<2; ++ii){
      int idx = ii*512 + tid;
      int rl = idx>>3, cs = (idx&7)^(rl&7);
      gload16(B0 + (size_t)(n0+rl)*1024 + kt*64 + cs*8, &sBK[buf][(ii*512+wv*64)*8]);
    }
  };
  auto stageBV = [&](int buf, int kt){
    #pragma unroll
    for (int ii=0; ii<2; ++ii){
      int idx = ii*512 + tid;
      int rl = idx>>3, cs = (idx&7)^(rl&7);
      gload16(B1 + (size_t)(n0+rl)*1024 + kt*64 + cs*8, &sBV[buf][(ii*512+wv*64)*8]);
    }
  };
  // prologue (tile 0), issue order matches in-loop absolute ordering
  stageA(0,0,0); stageBK(0,0); stageBV(0,0); stageA(0,0,1);

  b8v af[4][2], bk[2][2], bv[2][2];
  #pragma unroll 2
  for (int t=0; t<16; ++t){
    int cur = t&1, nxt = cur^1;
    // ---- phase 0: (A half0) x BK ----
    asm volatile("s_waitcnt vmcnt(4)" ::: "memory");
    __builtin_amdgcn_s_barrier();
    __builtin_amdgcn_sched_barrier(0);
    if (t < 15) stageA(nxt, t+1, 0);
    #pragma unroll
    for (int ml=0;ml<4;++ml){
      int lr = wr*64 + ml*16 + r;                   // half0
      #pragma unroll
      for (int ks=0;ks<2;++ks)
        af[ml][ks] = ldsf(&sA[cur][lr*64 + (((ks*4+g)^(r&7))*8)]);
    }
    #pragma unroll
    for (int nf=0;nf<2;++nf){
      int lr = wc*32 + nf*16 + r;
      #pragma unroll
      for (int ks=0;ks<2;++ks)
        bk[nf][ks] = ldsf(&sBK[cur][lr*64 + (((ks*4+g)^(r&7))*8)]);
    }
    __builtin_amdgcn_s_setprio(1);
    #pragma unroll
    for (int ml=0;ml<4;++ml){
      #pragma unroll
      for (int nf=0;nf<2;++nf){
        ac0[ml][nf] = mfma16(af[ml][0], bk[nf][0], ac0[ml][nf]);
        ac0[ml][nf] = mfma16(af[ml][1], bk[nf][1], ac0[ml][nf]);
      }
    }
    __builtin_amdgcn_s_setprio(0);
    // ---- phase 1: (A half0) x BV ----
    if (t < 15) { asm volatile("s_waitcnt vmcnt(4)" ::: "memory"); }
    else        { asm volatile("s_waitcnt vmcnt(2)" ::: "memory"); }
    __builtin_amdgcn_s_barrier();
    __builtin_amdgcn_sched_barrier(0);
    if (t < 15) stageBK(nxt, t+1);
    #pragma unroll
    for (int nf=0;nf<2;++nf){
      int lr = wc*32 + nf*16 + r;
      #pragma unroll
      for (int ks=0;ks<2;++ks)
        bv[nf][ks] = ldsf(&sBV[cur][lr*64 + (((ks*4+g)^(r&7))*8)]);
    }
    __builtin_amdgcn_s_setprio(1);
    #pragma unroll
    for (int ml=0;ml<4;++ml){
      #pragma unroll
      for (int nf=0;nf<2;++nf){
        ac1[ml][nf] = mfma16(af[ml][0], bv[nf][0], ac1[ml][nf]);
        ac1[ml][nf] = mfma16(af[ml][1], bv[nf][1], ac1[ml][nf]);
      }
    }
    __builtin_amdgcn_s_setprio(0);
    // ---- phase 2: (A half1) x BK ----
    if (t < 15) { asm volatile("s_waitcnt vmcnt(4)" ::: "memory"); }
    else        { asm volatile("s_waitcnt vmcnt(0)" ::: "memory"); }
    __builtin_amdgcn_s_barrier();
    __builtin_amdgcn_sched_barrier(0);
    if (t < 15) stageBV(nxt, t+1);
    #pragma unroll
    for (int ml=0;ml<4;++ml){
      int lr = 128 + wr*64 + ml*16 + r;             // half1
      #pragma unroll
      for (int ks=0;ks<2;++ks)
        af[ml][ks] = ldsf(&sA[cur][lr*64 + (((ks*4+g)^(r&7))*8)]);
    }
    __builtin_amdgcn_s_setprio(1);
    #pragma unroll
    for (int ml=0;ml<4;++ml){
      #pragma unroll
      for (int nf=0;nf<2;++nf){
        ac0[4+ml][nf] = mfma16(af[ml][0], bk[nf][0], ac0[4+ml][nf]);
        ac0[4+ml][nf] = mfma16(af[ml][1], bk[nf][1], ac0[4+ml][nf]);
      }
    }
    __builtin_amdgcn_s_setprio(0);
    // ---- phase 3: (A half1) x BV; no new LDS reads, no barrier ----
    if (t < 15) stageA(nxt, t+1, 1);
    __builtin_amdgcn_s_setprio(1);
    #pragma unroll
    for (int ml=0;ml<4;++ml){
      #pragma unroll
      for (int nf=0;nf<2;++nf){
        ac1[4+ml][nf] = mfma16(af[ml][0], bv[nf][0], ac1[4+ml][nf]);
        ac1[4+ml][nf] = mfma16(af[ml][1], bv[nf][1], ac1[4+ml][nf]);
      }
    }
    __builtin_amdgcn_s_setprio(0);
  }

  int b = m0 >> 12;
  #pragma unroll
  for (int mh=0; mh<2; ++mh){
    #pragma unroll
    for (int ml=0; ml<4; ++ml){
      #pragma unroll
      for (int nf=0; nf<2; ++nf){
        int m = m0 + wr*128 + mh*64 + ml*16 + g*4;
        int n = n0 + wc*32 + nf*16 + r;
        f4v a = ac0[mh*4+ml][nf];
        #pragma unroll
        for (int j=0;j<4;++j)
          C0[(size_t)(m+j)*1024 + n] = f2b(a[j]);
        f4v vvv = ac1[mh*4+ml][nf];
        int h = n >> 6, hd = n & 63;
        short4 vv = make_short4(f2b(vvv[0]), f2b(vvv[1]), f2b(vvv[2]), f2b(vvv[3]));
        *(short4*)&vt[(size_t)((b*16 + h)*64 + hd)*4096 + (m & 4095)] = vv;
      }
    }
  }
}

// ---------------- l-pass: ballot mask pack + l = sum(exp(s/8)) over unmasked ----------------
// pm word layout per (q-row): word w = (s&3)*2 + (s>>7), bit = (s>>2)&31
__global__ __launch_bounds__(256,2) void lsum_kernel(const short* __restrict__ qp, const short* __restrict__ kb,
                                                     const int* __restrict__ am, const int* __restrict__ kpm,
                                                     unsigned* __restrict__ pm, float* __restrict__ lpart){
  int bid = blockIdx.x;             // bh*16 + sc
  int sc = bid & 15, bh = bid >> 4;
  int b = bh >> 4, h = bh & 15;
  int s0 = sc*256;
  __shared__ short sQ[256*64];
  __shared__ short sK[256*64];
  __shared__ unsigned sPM[256*8];
  int tid=threadIdx.x, lane=tid&63, wv=tid>>6, g=lane>>4, r=lane&15;

  #pragma unroll
  for (int i=0;i<8;++i){
    int idx = i*256 + wv*64 + lane;
    int row = idx>>3, cbs = (idx&7)^(row&7);
    gload16(qp + (size_t)(b*256 + row)*1024 + h*64 + cbs*8, &sQ[(i*256+wv*64)*8]);
  }
  #pragma unroll
  for (int i=0;i<8;++i){
    int idx = i*256 + wv*64 + lane;
    int row = idx>>3, cbs = (idx&7)^(row&7);
    gload16(kb + (size_t)(b*4096 + s0 + row)*1024 + h*64 + cbs*8, &sK[(i*256+wv*64)*8]);
  }
  // key-padding row, lane l covers s = 4l..4l+3
  int4 kp = *(const int4*)(kpm + (size_t)b*4096 + s0 + lane*4);
  bool k0 = kp.x!=0, k1 = kp.y!=0, k2 = kp.z!=0, k3 = kp.w!=0;
  // wave-coalesced mask rows: 64 rows per wave
  #pragma unroll 4
  for (int i=0;i<64;++i){
    int row = wv*64 + i;
    const int4 t = *(const int4*)(am + (size_t)(bh*256 + row)*4096 + s0 + lane*4);
    unsigned long long m0 = __ballot(k0 || (t.x!=0));
    unsigned long long m1 = __ballot(k1 || (t.y!=0));
    unsigned long long m2 = __ballot(k2 || (t.z!=0));
    unsigned long long m3 = __ballot(k3 || (t.w!=0));
    if (lane < 8){
      int jj = lane>>1, hh = lane&1;
      unsigned long long bj = (jj==0)?m0:((jj==1)?m1:((jj==2)?m2:m3));
      unsigned w = (unsigned)(bj >> (hh*32));
      sPM[row*8 + lane] = w;
      pm[(size_t)bid*2048 + row*8 + lane] = w;
    }
  }
  __syncthreads();

  b8v a[4][2];
  #pragma unroll
  for (int mf=0;mf<4;++mf){
    #pragma unroll
    for (int ks=0;ks<2;++ks){
      int q = wv*64 + mf*16 + r;
      a[mf][ks] = ldsf(&sQ[q*64 + (((ks*4+g)^(q&7))*8)]);
    }
  }
  unsigned wmr[4][4][2];
  #pragma unroll
  for (int mf=0;mf<4;++mf){
    #pragma unroll
    for (int jq=0;jq<4;++jq){
      int q = wv*64 + mf*16 + g*4 + jq;
      wmr[mf][jq][0] = sPM[q*8 + (r&3)*2 + 0];
      wmr[mf][jq][1] = sPM[q*8 + (r&3)*2 + 1];
    }
  }
  float lacc[4][4];
  #pragma unroll
  for (int mf=0;mf<4;++mf){
    #pragma unroll
    for (int j=0;j<4;++j) lacc[mf][j] = 0.f;
  }
  f4v z = {0.f,0.f,0.f,0.f};
  #pragma unroll 4
  for (int nf=0;nf<16;++nf){
    int srow = nf*16 + r;
    b8v b0 = ldsf(&sK[srow*64 + ((g^(srow&7))*8)]);
    b8v b1 = ldsf(&sK[srow*64 + (((4+g)^(srow&7))*8)]);
    f4v acc[4];
    #pragma unroll
    for (int mf=0;mf<4;++mf){
      acc[mf] = mfma16(a[mf][0], b0, z);
      acc[mf] = mfma16(a[mf][1], b1, acc[mf]);
    }
    int bitp = 4*(nf&7) + (r>>2);
    #pragma unroll
    for (int mf=0;mf<4;++mf){
      #pragma unroll
      for (int j=0;j<4;++j){
        bool mskd = (wmr[mf][j][nf>>3] >> bitp) & 1u;
        lacc[mf][j] += mskd ? 0.f : __expf(acc[mf][j]*0.125f);
      }
    }
  }
  #pragma unroll
  for (int off=1; off<16; off<<=1){
    #pragma unroll
    for (int mf=0;mf<4;++mf){
      #pragma unroll
      for (int j=0;j<4;++j) lacc[mf][j] += __shfl_xor(lacc[mf][j], off);
    }
  }
  if (r == 0){
    #pragma unroll
    for (int mf=0;mf<4;++mf){
      #pragma unroll
      for (int j=0;j<4;++j){
        int q = wv*64 + mf*16 + g*4 + j;
        lpart[(size_t)bid*256 + q] = lacc[mf][j];
      }
    }
  }
}

// ---------------- combine chunk sums -> inv l (0 for dead rows) ----------------
__global__ void lcomb_kernel(const float* __restrict__ lpart, float* __restrict__ linv){
  int row = blockIdx.x*256 + threadIdx.x;   // B*H*Q = 16384
  int q = row & 255, bh = row >> 8;
  float l = 0.f;
  #pragma unroll
  for (int sc=0; sc<16; ++sc) l += lpart[(size_t)(bh*16+sc)*256 + q];
  linv[row] = (l > 0.f) ? (1.0f/l) : 0.f;
}

// -------- phase2: SBLK=128, head-pipelined (dbuf K/V, reg-prefetch Q/pm/iv); swapped QK^T --------
__global__ __launch_bounds__(512,4) void attn_pv_kernel(const short* __restrict__ qp, const short* __restrict__ kb,
                                                        const short* __restrict__ vt, const unsigned* __restrict__ pm,
                                                        const float* __restrict__ linv, short* __restrict__ opart,
                                                        float* __restrict__ out2){
  int bid = blockIdx.x;             // ((b*4+qt)*32 + sc)
  int sc = bid & 31, qt = (bid>>5)&3, b = bid>>7;
  int s0 = sc*128, q0 = qt*64;
  int half = sc & 1, scq = sc >> 1;
  __shared__ short sK[2][128*64];   // becomes P (64q x 128s) after QK^T
  __shared__ short sV[2][64*128];
  __shared__ unsigned sPM[2][64*4];
  int tid=threadIdx.x, lane=tid&63, wv=tid>>6, g=lane>>4, r=lane&15;
  int wq = wv>>2, ws = wv&3;
  f4v z = {0.f,0.f,0.f,0.f};
  float macc[2][2][4];              // [sb][qb][j]
  #pragma unroll
  for (int sb=0;sb<2;++sb){
    #pragma unroll
    for (int qb=0;qb<2;++qb){
      #pragma unroll
      for (int j=0;j<4;++j) macc[sb][qb][j] = 0.f;
    }
  }

  auto stageKV = [&](int buf, int h){   // 4 gload_lds per thread
    int bh = b*16 + h;
    #pragma unroll
    for (int i=0;i<2;++i){
      int idx = i*512 + tid;
      int row = idx>>3, cbs = (idx&7)^(row&7);
      gload16(kb + (size_t)(b*4096 + s0 + row)*1024 + h*64 + cbs*8, &sK[buf][(i*512+wv*64)*8]);
    }
    #pragma unroll
    for (int i=0;i<2;++i){
      int idx = i*512 + tid;
      int row = idx>>4, sl = idx&15, sls = sl^(row&7);
      gload16(vt + (size_t)(bh*64 + row)*4096 + s0 + sls*8, &sV[buf][(i*512+wv*64)*8]);
    }
  };
  auto pmld = [&](int h)->unsigned {    // wave-uniform: all 512 threads load
    int t = tid & 255;
    return pm[(size_t)((b*16+h)*16+scq)*2048 + (q0 + (t>>2))*8 + (t&3)*2 + half];
  };

  // prologue: head 0 fully prefetched
  stageKV(0, 0);
  unsigned pmv = pmld(0);
  b8v qf00 = gldf(qp + (size_t)(b*256 + q0 + wq*32 + r)*1024 + 0*64 + (0*4+g)*8);
  b8v qf01 = gldf(qp + (size_t)(b*256 + q0 + wq*32 + r)*1024 + 0*64 + (1*4+g)*8);
  b8v qf10 = gldf(qp + (size_t)(b*256 + q0 + wq*32 + 16 + r)*1024 + 0*64 + (0*4+g)*8);
  b8v qf11 = gldf(qp + (size_t)(b*256 + q0 + wq*32 + 16 + r)*1024 + 0*64 + (1*4+g)*8);
  float iv0 = linv[(size_t)(b*16)*256 + q0 + wq*32 + r];
  float iv1 = linv[(size_t)(b*16)*256 + q0 + wq*32 + 16 + r];

  #pragma unroll 2
  for (int h=0; h<16; ++h){
    int cur = h&1, nxt = cur^1;
    // ---- top: head h's loads landed (issued a full iteration ago) ----
    asm volatile("s_waitcnt vmcnt(0)" ::: "memory");
    if (tid < 256) sPM[cur][tid] = pmv;
    asm volatile("s_waitcnt lgkmcnt(0)" ::: "memory");
    __builtin_amdgcn_s_barrier();
    __builtin_amdgcn_sched_barrier(0);

    // ---- prefetch head h+1 (hidden under this head's compute) ----
    b8v qn00, qn01, qn10, qn11; unsigned pmvn = 0; float ivn0 = 0.f, ivn1 = 0.f;
    if (h < 15){
      stageKV(nxt, h+1);
      pmvn = pmld(h+1);
      size_t qb0 = (size_t)(b*256 + q0 + wq*32 + r)*1024 + (h+1)*64;
      size_t qb1 = (size_t)(b*256 + q0 + wq*32 + 16 + r)*1024 + (h+1)*64;
      qn00 = gldf(qp + qb0 + g*8);       qn01 = gldf(qp + qb0 + (4+g)*8);
      qn10 = gldf(qp + qb1 + g*8);       qn11 = gldf(qp + qb1 + (4+g)*8);
      ivn0 = linv[(size_t)(b*16+h+1)*256 + q0 + wq*32 + r];
      ivn1 = linv[(size_t)(b*16+h+1)*256 + q0 + wq*32 + 16 + r];
    }

    // ---- QK^T swapped: acc[s][q] = mfma(K, Q) ----
    f4v accs[2][2];
    __builtin_amdgcn_s_setprio(1);
    #pragma unroll
    for (int sb=0;sb<2;++sb){
      int srow = ws*32 + sb*16 + r;
      b8v k0 = ldsf(&sK[cur][srow*64 + ((g^(srow&7))*8)]);
      b8v k1 = ldsf(&sK[cur][srow*64 + (((4+g)^(srow&7))*8)]);
      accs[sb][0] = mfma16(k0, qf00, z);
      accs[sb][0] = mfma16(k1, qf01, accs[sb][0]);
      accs[sb][1] = mfma16(k0, qf10, z);
      accs[sb][1] = mfma16(k1, qf11, accs[sb][1]);
    }
    __builtin_amdgcn_s_setprio(0);
    lds_barrier();     // B1: sK[cur] reads done, safe to overlay P

    // ---- softmax; write P[q][s] into sK[cur] (b64 packed writes) ----
    float iv[2]; iv[0] = iv0; iv[1] = iv1;
    unsigned wmq[2][4];
    #pragma unroll
    for (int qb=0;qb<2;++qb){
      #pragma unroll
      for (int j=0;j<4;++j)
        wmq[qb][j] = sPM[cur][(wq*32+qb*16+r)*4 + j];
    }
    short* P = &sK[cur][0];
    #pragma unroll
    for (int sb=0;sb<2;++sb){
      int bitp = ws*8 + sb*4 + g;
      #pragma unroll
      for (int qb=0;qb<2;++qb){
        float pj[4];
        #pragma unroll
        for (int j=0;j<4;++j){
          bool mskd = (wmq[qb][j] >> bitp) & 1u;
          pj[j] = mskd ? 0.f : __expf(accs[sb][qb][j]*0.125f) * iv[qb];
          macc[sb][qb][j] += pj[j];
        }
        int q = wq*32 + qb*16 + r;
        unsigned lo = ((unsigned)(unsigned short)f2b(pj[0])) | (((unsigned)(unsigned short)f2b(pj[1]))<<16);
        unsigned hi = ((unsigned)(unsigned short)f2b(pj[2])) | (((unsigned)(unsigned short)f2b(pj[3]))<<16);
        int sbase = (ws*32 + sb*16 + g*4) ^ ((q&7)<<3);
        uint2 pk; pk.x = lo; pk.y = hi;
        *(uint2*)&P[q*128 + sbase] = pk;
      }
    }
    lds_barrier();     // B2: P visible

    // ---- PV: O[q][d] += P[q][s] * V[s][d] (s over 128) ----
    f4v acco[2]; acco[0]=z; acco[1]=z;
    __builtin_amdgcn_s_setprio(1);
    #pragma unroll
    for (int ks=0;ks<4;++ks){
      int vrow = ws*16 + r;
      b8v bv = ldsf(&sV[cur][vrow*128 + ((ks*32+g*8) ^ ((vrow&7)<<3))]);
      #pragma unroll
      for (int mf=0;mf<2;++mf){
        int prow = wq*32 + mf*16 + r;
        b8v ap = ldsf(&P[prow*128 + ((ks*32+g*8) ^ ((prow&7)<<3))]);
        acco[mf] = mfma16(ap, bv, acco[mf]);
      }
    }
    __builtin_amdgcn_s_setprio(0);
    #pragma unroll
    for (int mf=0;mf<2;++mf){
      #pragma unroll
      for (int j=0;j<4;++j)
        opart[((size_t)sc*1024 + b*256 + q0 + wq*32 + mf*16 + g*4 + j)*1024 + h*64 + ws*16 + r] = f2b(acco[mf][j]);
    }
    // no B3: [cur] is only overwritten by the stage issued AFTER the next top barrier

    // rotate prefetched registers
    qf00 = qn00; qf01 = qn01; qf10 = qn10; qf11 = qn11;
    pmv = pmvn; iv0 = ivn0; iv1 = ivn1;
  }

  // ---- out2 = head-mean, coalesced float4 stores ----
  #pragma unroll
  for (int sb=0;sb<2;++sb){
    #pragma unroll
    for (int qb=0;qb<2;++qb){
      int q = q0 + wq*32 + qb*16 + r;
      float4 o = make_float4(macc[sb][qb][0]*0.0625f, macc[sb][qb][1]*0.0625f,
                             macc[sb][qb][2]*0.0625f, macc[sb][qb][3]*0.0625f);
      *(float4*)&out2[(size_t)(b*256 + q)*4096 + s0 + ws*32 + sb*16 + g*4] = o;
    }
  }
}

// ---------------- launcher ----------------
extern "C" void kernel_launch(void* const* d_in, const int* in_sizes, int n_in,
                              void* d_out, int out_size, void* d_ws, size_t ws_size,
                              hipStream_t stream){
  const float* x       = (const float*)d_in[0];
  const float* queries = (const float*)d_in[1];
  const int*   am      = (const int*)d_in[2];
  const int*   kpm     = (const int*)d_in[3];
  const float* Wq      = (const float*)d_in[4];
  const float* Wk      = (const float*)d_in[5];
  const float* Wv      = (const float*)d_in[6];
  const float* Wo      = (const float*)d_in[7];
  const float* ln1g    = (const float*)d_in[8];
  const float* ln1b    = (const float*)d_in[9];
  const float* ln2g    = (const float*)d_in[10];
  const float* ln2b    = (const float*)d_in[11];
  float* out0 = (float*)d_out;
  float* out2 = out0 + (size_t)4*256*1024;
  char* ws = (char*)d_ws;

  size_t off = 0;
  auto alloc = [&](size_t bytes){ void* p = ws + off; off += (bytes + 255) & ~(size_t)255; return p; };
  short*    xn   = (short*)alloc(33554432);   // (B*S, D) bf16
  short*    kb   = (short*)alloc(33554432);   // (B,S,D) bf16
  short*    vt   = (short*)alloc(33554432);   // (B,H,hd,S) bf16 — written directly by V GEMM
  short*    wqb  = (short*)alloc(2097152);
  short*    wkb  = (short*)alloc(2097152);
  short*    wvb  = (short*)alloc(2097152);
  short*    wob  = (short*)alloc(2097152);
  short*    qbf  = (short*)alloc(2097152);    // queries bf16
  short*    qpj  = (short*)alloc(2097152);    // projected q bf16
  unsigned* pmw  = (unsigned*)alloc(8388608); // packed mask bits, [bh*16+sc256][256 q][8 words]
  float*    lpart= (float*)alloc(1048576);    // per-chunk l sums [1024][256]
  float*    linv = (float*)alloc(65536);      // 1/l (or 0)
  short*    opart= (short*)alloc(67108864);   // O partials per s-chunk: [32][B*Q][1024] bf16
  short*    onb  = (short*)alloc(2097152);    // ln2 output bf16

  prep_kernel<<<21504,256,0,stream>>>(x, ln1g, ln1b, xn,
                                      queries, Wq, Wk, Wv, Wo, qbf, wqb, wkb, wvb, wob);
  gemm_dual8<<<dim3(64,8),512,0,stream>>>(xn, wkb, wvb, kb, vt);
  gemm_small<0><<<dim3(16,16),256,0,stream>>>(qbf, wqb, qpj, 1024, 1024, 1024);
  lsum_kernel<<<1024,256,0,stream>>>(qpj, kb, am, kpm, pmw, lpart);
  lcomb_kernel<<<64,256,0,stream>>>(lpart, linv);
  attn_pv_kernel<<<512,512,0,stream>>>(qpj, kb, vt, pmw, linv, opart, out2);
  ln_reduce_kernel<<<1024,256,0,stream>>>(opart, ln2g, ln2b, onb);
  gemm_small<1><<<dim3(16,16),256,0,stream>>>(onb, wob, out0, 1024, 1024, 1024);
}

// Round 14
// 316.978 us; speedup vs baseline: 1.1923x; 1.1923x over previous
//
#include <hip/hip_runtime.h>
#include <math.h>

#define DEV __device__ __forceinline__

typedef float  f4v  __attribute__((ext_vector_type(4)));
typedef __bf16 b8v  __attribute__((ext_vector_type(8)));
typedef short  s8v  __attribute__((ext_vector_type(8)));

DEV short f2b(float f){ __bf16 h = (__bf16)f; return __builtin_bit_cast(short, h); }
DEV float b2f(short s){ __bf16 h = __builtin_bit_cast(__bf16, s); return (float)h; }

DEV void gload16(const void* g, void* l){
  __builtin_amdgcn_global_load_lds((const __attribute__((address_space(1))) void*)g,
                                   (__attribute__((address_space(3))) void*)l, 16, 0, 0);
}

DEV b8v ldsf(const short* p){ return __builtin_bit_cast(b8v, *(const s8v*)p); }

DEV f4v mfma16(b8v a, b8v b, f4v c){ return __builtin_amdgcn_mfma_f32_16x16x32_bf16(a, b, c, 0, 0, 0); }

// LDS-only barrier: does NOT drain vmcnt (m201 pattern).
DEV void lds_barrier(){
  asm volatile("s_waitcnt lgkmcnt(0)" ::: "memory");
  __builtin_amdgcn_s_barrier();
}

// ---------------- prep: ln(x) -> xn  AND  f32->bf16 converts, one launch ----------------
__global__ __launch_bounds__(256) void prep_kernel(const float* __restrict__ x, const float* __restrict__ ln1g,
                                                   const float* __restrict__ ln1b, short* __restrict__ xn,
                                                   const float* __restrict__ s0, const float* __restrict__ s1,
                                                   const float* __restrict__ s2, const float* __restrict__ s3,
                                                   const float* __restrict__ s4,
                                                   short* __restrict__ d0, short* __restrict__ d1,
                                                   short* __restrict__ d2, short* __restrict__ d3,
                                                   short* __restrict__ d4){
  int bid = blockIdx.x, tid = threadIdx.x;
  if (bid < 5120){
    int i = bid*256 + tid;   // 5 * 262144 float4s
    int buf = i >> 18, j = i & 262143;
    const float* s = (buf==0)?s0:(buf==1)?s1:(buf==2)?s2:(buf==3)?s3:s4;
    short*       d = (buf==0)?d0:(buf==1)?d1:(buf==2)?d2:(buf==3)?d3:d4;
    float4 v = ((const float4*)s)[j];
    ((short4*)d)[j] = make_short4(f2b(v.x), f2b(v.y), f2b(v.z), f2b(v.w));
    return;
  }
  int row = bid - 5120;
  const float4 v = ((const float4*)(x + (size_t)row*1024))[tid];
  float s = v.x + v.y + v.z + v.w;
  #pragma unroll
  for (int off=1; off<64; off<<=1) s += __shfl_xor(s, off);
  __shared__ float red[4];
  if ((tid&63)==0) red[tid>>6] = s;
  __syncthreads();
  float mu = (red[0]+red[1]+red[2]+red[3]) * (1.0f/1024.0f);
  float e0=v.x-mu, e1=v.y-mu, e2=v.z-mu, e3=v.w-mu;
  float q = e0*e0 + e1*e1 + e2*e2 + e3*e3;
  #pragma unroll
  for (int off=1; off<64; off<<=1) q += __shfl_xor(q, off);
  __syncthreads();
  if ((tid&63)==0) red[tid>>6] = q;
  __syncthreads();
  float rs = rsqrtf((red[0]+red[1]+red[2]+red[3]) * (1.0f/1024.0f) + 1e-5f);
  float4 g4 = ((const float4*)ln1g)[tid];
  float4 b4 = ((const float4*)ln1b)[tid];
  short4 o = make_short4(f2b(e0*rs*g4.x + b4.x), f2b(e1*rs*g4.y + b4.y),
                         f2b(e2*rs*g4.z + b4.z), f2b(e3*rs*g4.w + b4.w));
  ((short4*)(xn + (size_t)row*1024))[tid] = o;
}

// ---------------- LayerNorm fused with 32-slice sum reduce (bf16 O-partials) ----------------
__global__ __launch_bounds__(256) void ln_reduce_kernel(const short* __restrict__ opart, const float* __restrict__ gg,
                                                        const float* __restrict__ bb, short* __restrict__ out){
  int row = blockIdx.x, tid = threadIdx.x;
  float a0=0.f, a1=0.f, a2=0.f, a3=0.f;
  #pragma unroll
  for (int sc=0; sc<32; ++sc){
    short4 t = ((const short4*)(opart + ((size_t)sc*1024 + row)*1024))[tid];
    a0 += b2f(t.x); a1 += b2f(t.y); a2 += b2f(t.z); a3 += b2f(t.w);
  }
  float s = a0 + a1 + a2 + a3;
  #pragma unroll
  for (int off=1; off<64; off<<=1) s += __shfl_xor(s, off);
  __shared__ float red[4];
  if ((tid&63)==0) red[tid>>6] = s;
  __syncthreads();
  float mu = (red[0]+red[1]+red[2]+red[3]) * (1.0f/1024.0f);
  float d0=a0-mu, d1=a1-mu, d2=a2-mu, d3=a3-mu;
  float q = d0*d0 + d1*d1 + d2*d2 + d3*d3;
  #pragma unroll
  for (int off=1; off<64; off<<=1) q += __shfl_xor(q, off);
  __syncthreads();
  if ((tid&63)==0) red[tid>>6] = q;
  __syncthreads();
  float rs = rsqrtf((red[0]+red[1]+red[2]+red[3]) * (1.0f/1024.0f) + 1e-5f);
  float4 g4 = ((const float4*)gg)[tid];
  float4 b4 = ((const float4*)bb)[tid];
  short4 o = make_short4(f2b(d0*rs*g4.x + b4.x), f2b(d1*rs*g4.y + b4.y),
                         f2b(d2*rs*g4.z + b4.z), f2b(d3*rs*g4.w + b4.w));
  ((short4*)(out + (size_t)row*1024))[tid] = o;
}

// ---------------- small GEMM (M,N ~1024): 64x64 tile, BK=64, counted-vmcnt 2-phase ----------------
template<int OUTF32>
__global__ __launch_bounds__(256) void gemm_small(const short* __restrict__ A, const short* __restrict__ B,
                                                  void* __restrict__ C, int M, int N, int K){
  __shared__ short sA[2][64*64];
  __shared__ short sB[2][64*64];
  int tid=threadIdx.x, lane=tid&63, wv=tid>>6, g=lane>>4, r=lane&15;
  int wr=wv>>1, wc=wv&1;
  int m0=blockIdx.x*64, n0=blockIdx.y*64;
  f4v z = {0.f,0.f,0.f,0.f};
  f4v acc[2][2];
  #pragma unroll
  for (int i=0;i<2;++i){
    #pragma unroll
    for (int j=0;j<2;++j) acc[i][j]=z;
  }
  auto stage = [&](int buf, int kt){   // exactly 4 VMEM ops per thread
    #pragma unroll
    for (int i=0;i<2;++i){
      int idx = i*256 + tid;
      int row = idx>>3, cbs = (idx&7)^(row&7);
      gload16(A + (size_t)(m0+row)*K + kt*64 + cbs*8, &sA[buf][(i*256+wv*64)*8]);
      gload16(B + (size_t)(n0+row)*K + kt*64 + cbs*8, &sB[buf][(i*256+wv*64)*8]);
    }
  };
  int nkt = K >> 6;
  stage(0, 0);
  for (int kt=0; kt<nkt; ++kt){
    int cur = kt & 1;
    if (kt+1 < nkt){
      stage(cur^1, kt+1);
      asm volatile("s_waitcnt vmcnt(4)" ::: "memory");  // cur tile landed; prefetch in flight
    } else {
      asm volatile("s_waitcnt vmcnt(0)" ::: "memory");
    }
    __builtin_amdgcn_s_barrier();
    b8v af[2][2], bf[2][2];
    #pragma unroll
    for (int mf=0;mf<2;++mf){
      #pragma unroll
      for (int ks=0;ks<2;++ks){
        int ra = wr*32 + mf*16 + r;
        int rb = wc*32 + mf*16 + r;
        af[mf][ks] = ldsf(&sA[cur][ra*64 + (((ks*4+g)^(ra&7))*8)]);
        bf[mf][ks] = ldsf(&sB[cur][rb*64 + (((ks*4+g)^(rb&7))*8)]);
      }
    }
    #pragma unroll
    for (int mf=0;mf<2;++mf){
      #pragma unroll
      for (int nf=0;nf<2;++nf){
        acc[mf][nf] = mfma16(af[mf][0], bf[nf][0], acc[mf][nf]);
        acc[mf][nf] = mfma16(af[mf][1], bf[nf][1], acc[mf][nf]);
      }
    }
    asm volatile("s_waitcnt lgkmcnt(0)" ::: "memory");  // own LDS reads done
    __builtin_amdgcn_s_barrier();                       // everyone done -> safe to re-stage
  }
  #pragma unroll
  for (int mf=0;mf<2;++mf){
    #pragma unroll
    for (int nf=0;nf<2;++nf){
      #pragma unroll
      for (int j=0;j<4;++j){
        int m = m0 + wr*32 + mf*16 + g*4 + j;
        int n = n0 + wc*32 + nf*16 + r;
        if (OUTF32) ((float*)C)[(size_t)m*N + n] = acc[mf][nf][j];
        else        ((short*)C)[(size_t)m*N + n] = f2b(acc[mf][nf][j]);
      }
    }
  }
}

// ======== fused K+V 8-phase GEMM: BM=256, BN=128 per output, BK=64, counted vmcnt ========
__global__ __launch_bounds__(512,1) void gemm_dual8(const short* __restrict__ A, const short* __restrict__ B0,
                                                    const short* __restrict__ B1, short* __restrict__ C0,
                                                    short* __restrict__ vt){
  __shared__ short sA[2][256*64];   // 64 KB  (halves: rows 0-127 / 128-255 of lds-rows)
  __shared__ short sBK[2][128*64];  // 32 KB
  __shared__ short sBV[2][128*64];  // 32 KB
  int tid=threadIdx.x, lane=tid&63, wv=tid>>6, g=lane>>4, r=lane&15;
  int wr=wv>>2, wc=wv&3;            // 2M x 4N waves; wave tile 128m x 32n per output
  int m0 = blockIdx.x*256, n0 = blockIdx.y*128;
  f4v z = {0.f,0.f,0.f,0.f};
  f4v ac0[8][2], ac1[8][2];
  #pragma unroll
  for (int i=0;i<8;++i){
    #pragma unroll
    for (int j=0;j<2;++j){ ac0[i][j]=z; ac1[i][j]=z; }
  }
  auto stageA = [&](int buf, int kt, int h){
    #pragma unroll
    for (int ii=0; ii<2; ++ii){
      int idx = ii*512 + tid;                       // 0..1023 within half
      int rl = idx>>3, cs = (idx&7)^(rl&7);
      int rowA = (((rl>>6)&1)<<7) | (h<<6) | (rl&63);
      gload16(A + (size_t)(m0+rowA)*1024 + kt*64 + cs*8,
              &sA[buf][(h*1024 + ii*512 + wv*64)*8]);
    }
  };
  auto stageBK = [&](int buf, int kt){
    #pragma unroll
    for (int ii=0; ii<2; ++ii){
      int idx = ii*512 + tid;
      int rl = idx>>3, cs = (idx&7)^(rl&7);
      gload16(B0 + (size_t)(n0+rl)*1024 + kt*64 + cs*8, &sBK[buf][(ii*512+wv*64)*8]);
    }
  };
  auto stageBV = [&](int buf, int kt){
    #pragma unroll
    for (int ii=0; ii<2; ++ii){
      int idx = ii*512 + tid;
      int rl = idx>>3, cs = (idx&7)^(rl&7);
      gload16(B1 + (size_t)(n0+rl)*1024 + kt*64 + cs*8, &sBV[buf][(ii*512+wv*64)*8]);
    }
  };
  // prologue (tile 0), issue order matches in-loop absolute ordering
  stageA(0,0,0); stageBK(0,0); stageBV(0,0); stageA(0,0,1);

  b8v af[4][2], bk[2][2], bv[2][2];
  #pragma unroll 2
  for (int t=0; t<16; ++t){
    int cur = t&1, nxt = cur^1;
    // ---- phase 0: (A half0) x BK ----
    asm volatile("s_waitcnt vmcnt(4)" ::: "memory");
    __builtin_amdgcn_s_barrier();
    __builtin_amdgcn_sched_barrier(0);
    if (t < 15) stageA(nxt, t+1, 0);
    #pragma unroll
    for (int ml=0;ml<4;++ml){
      int lr = wr*64 + ml*16 + r;                   // half0
      #pragma unroll
      for (int ks=0;ks<2;++ks)
        af[ml][ks] = ldsf(&sA[cur][lr*64 + (((ks*4+g)^(r&7))*8)]);
    }
    #pragma unroll
    for (int nf=0;nf<2;++nf){
      int lr = wc*32 + nf*16 + r;
      #pragma unroll
      for (int ks=0;ks<2;++ks)
        bk[nf][ks] = ldsf(&sBK[cur][lr*64 + (((ks*4+g)^(r&7))*8)]);
    }
    __builtin_amdgcn_s_setprio(1);
    #pragma unroll
    for (int ml=0;ml<4;++ml){
      #pragma unroll
      for (int nf=0;nf<2;++nf){
        ac0[ml][nf] = mfma16(af[ml][0], bk[nf][0], ac0[ml][nf]);
        ac0[ml][nf] = mfma16(af[ml][1], bk[nf][1], ac0[ml][nf]);
      }
    }
    __builtin_amdgcn_s_setprio(0);
    // ---- phase 1: (A half0) x BV ----
    if (t < 15) { asm volatile("s_waitcnt vmcnt(4)" ::: "memory"); }
    else        { asm volatile("s_waitcnt vmcnt(2)" ::: "memory"); }
    __builtin_amdgcn_s_barrier();
    __builtin_amdgcn_sched_barrier(0);
    if (t < 15) stageBK(nxt, t+1);
    #pragma unroll
    for (int nf=0;nf<2;++nf){
      int lr = wc*32 + nf*16 + r;
      #pragma unroll
      for (int ks=0;ks<2;++ks)
        bv[nf][ks] = ldsf(&sBV[cur][lr*64 + (((ks*4+g)^(r&7))*8)]);
    }
    __builtin_amdgcn_s_setprio(1);
    #pragma unroll
    for (int ml=0;ml<4;++ml){
      #pragma unroll
      for (int nf=0;nf<2;++nf){
        ac1[ml][nf] = mfma16(af[ml][0], bv[nf][0], ac1[ml][nf]);
        ac1[ml][nf] = mfma16(af[ml][1], bv[nf][1], ac1[ml][nf]);
      }
    }
    __builtin_amdgcn_s_setprio(0);
    // ---- phase 2: (A half1) x BK ----
    if (t < 15) { asm volatile("s_waitcnt vmcnt(4)" ::: "memory"); }
    else        { asm volatile("s_waitcnt vmcnt(0)" ::: "memory"); }
    __builtin_amdgcn_s_barrier();
    __builtin_amdgcn_sched_barrier(0);
    if (t < 15) stageBV(nxt, t+1);
    #pragma unroll
    for (int ml=0;ml<4;++ml){
      int lr = 128 + wr*64 + ml*16 + r;             // half1
      #pragma unroll
      for (int ks=0;ks<2;++ks)
        af[ml][ks] = ldsf(&sA[cur][lr*64 + (((ks*4+g)^(r&7))*8)]);
    }
    __builtin_amdgcn_s_setprio(1);
    #pragma unroll
    for (int ml=0;ml<4;++ml){
      #pragma unroll
      for (int nf=0;nf<2;++nf){
        ac0[4+ml][nf] = mfma16(af[ml][0], bk[nf][0], ac0[4+ml][nf]);
        ac0[4+ml][nf] = mfma16(af[ml][1], bk[nf][1], ac0[4+ml][nf]);
      }
    }
    __builtin_amdgcn_s_setprio(0);
    // ---- phase 3: (A half1) x BV; no new LDS reads, no barrier ----
    if (t < 15) stageA(nxt, t+1, 1);
    __builtin_amdgcn_s_setprio(1);
    #pragma unroll
    for (int ml=0;ml<4;++ml){
      #pragma unroll
      for (int nf=0;nf<2;++nf){
        ac1[4+ml][nf] = mfma16(af[ml][0], bv[nf][0], ac1[4+ml][nf]);
        ac1[4+ml][nf] = mfma16(af[ml][1], bv[nf][1], ac1[4+ml][nf]);
      }
    }
    __builtin_amdgcn_s_setprio(0);
  }

  int b = m0 >> 12;
  #pragma unroll
  for (int mh=0; mh<2; ++mh){
    #pragma unroll
    for (int ml=0; ml<4; ++ml){
      #pragma unroll
      for (int nf=0; nf<2; ++nf){
        int m = m0 + wr*128 + mh*64 + ml*16 + g*4;
        int n = n0 + wc*32 + nf*16 + r;
        f4v a = ac0[mh*4+ml][nf];
        #pragma unroll
        for (int j=0;j<4;++j)
          C0[(size_t)(m+j)*1024 + n] = f2b(a[j]);
        f4v vvv = ac1[mh*4+ml][nf];
        int h = n >> 6, hd = n & 63;
        short4 vv = make_short4(f2b(vvv[0]), f2b(vvv[1]), f2b(vvv[2]), f2b(vvv[3]));
        *(short4*)&vt[(size_t)((b*16 + h)*64 + hd)*4096 + (m & 4095)] = vv;
      }
    }
  }
}

// ---------------- l-pass: ballot mask pack + l = sum(exp(s/8)) over unmasked ----------------
// pm word layout per (q-row): word w = (s&3)*2 + (s>>7), bit = (s>>2)&31
__global__ __launch_bounds__(256,2) void lsum_kernel(const short* __restrict__ qp, const short* __restrict__ kb,
                                                     const int* __restrict__ am, const int* __restrict__ kpm,
                                                     unsigned* __restrict__ pm, float* __restrict__ lpart){
  int bid = blockIdx.x;             // bh*16 + sc
  int sc = bid & 15, bh = bid >> 4;
  int b = bh >> 4, h = bh & 15;
  int s0 = sc*256;
  __shared__ short sQ[256*64];
  __shared__ short sK[256*64];
  __shared__ unsigned sPM[256*8];
  int tid=threadIdx.x, lane=tid&63, wv=tid>>6, g=lane>>4, r=lane&15;

  #pragma unroll
  for (int i=0;i<8;++i){
    int idx = i*256 + wv*64 + lane;
    int row = idx>>3, cbs = (idx&7)^(row&7);
    gload16(qp + (size_t)(b*256 + row)*1024 + h*64 + cbs*8, &sQ[(i*256+wv*64)*8]);
  }
  #pragma unroll
  for (int i=0;i<8;++i){
    int idx = i*256 + wv*64 + lane;
    int row = idx>>3, cbs = (idx&7)^(row&7);
    gload16(kb + (size_t)(b*4096 + s0 + row)*1024 + h*64 + cbs*8, &sK[(i*256+wv*64)*8]);
  }
  // key-padding row, lane l covers s = 4l..4l+3
  int4 kp = *(const int4*)(kpm + (size_t)b*4096 + s0 + lane*4);
  bool k0 = kp.x!=0, k1 = kp.y!=0, k2 = kp.z!=0, k3 = kp.w!=0;
  // wave-coalesced mask rows: 64 rows per wave
  #pragma unroll 4
  for (int i=0;i<64;++i){
    int row = wv*64 + i;
    const int4 t = *(const int4*)(am + (size_t)(bh*256 + row)*4096 + s0 + lane*4);
    unsigned long long m0 = __ballot(k0 || (t.x!=0));
    unsigned long long m1 = __ballot(k1 || (t.y!=0));
    unsigned long long m2 = __ballot(k2 || (t.z!=0));
    unsigned long long m3 = __ballot(k3 || (t.w!=0));
    if (lane < 8){
      int jj = lane>>1, hh = lane&1;
      unsigned long long bj = (jj==0)?m0:((jj==1)?m1:((jj==2)?m2:m3));
      unsigned w = (unsigned)(bj >> (hh*32));
      sPM[row*8 + lane] = w;
      pm[(size_t)bid*2048 + row*8 + lane] = w;
    }
  }
  __syncthreads();

  b8v a[4][2];
  #pragma unroll
  for (int mf=0;mf<4;++mf){
    #pragma unroll
    for (int ks=0;ks<2;++ks){
      int q = wv*64 + mf*16 + r;
      a[mf][ks] = ldsf(&sQ[q*64 + (((ks*4+g)^(q&7))*8)]);
    }
  }
  unsigned wmr[4][4][2];
  #pragma unroll
  for (int mf=0;mf<4;++mf){
    #pragma unroll
    for (int jq=0;jq<4;++jq){
      int q = wv*64 + mf*16 + g*4 + jq;
      wmr[mf][jq][0] = sPM[q*8 + (r&3)*2 + 0];
      wmr[mf][jq][1] = sPM[q*8 + (r&3)*2 + 1];
    }
  }
  float lacc[4][4];
  #pragma unroll
  for (int mf=0;mf<4;++mf){
    #pragma unroll
    for (int j=0;j<4;++j) lacc[mf][j] = 0.f;
  }
  f4v z = {0.f,0.f,0.f,0.f};
  #pragma unroll 4
  for (int nf=0;nf<16;++nf){
    int srow = nf*16 + r;
    b8v b0 = ldsf(&sK[srow*64 + ((g^(srow&7))*8)]);
    b8v b1 = ldsf(&sK[srow*64 + (((4+g)^(srow&7))*8)]);
    f4v acc[4];
    #pragma unroll
    for (int mf=0;mf<4;++mf){
      acc[mf] = mfma16(a[mf][0], b0, z);
      acc[mf] = mfma16(a[mf][1], b1, acc[mf]);
    }
    int bitp = 4*(nf&7) + (r>>2);
    #pragma unroll
    for (int mf=0;mf<4;++mf){
      #pragma unroll
      for (int j=0;j<4;++j){
        bool mskd = (wmr[mf][j][nf>>3] >> bitp) & 1u;
        lacc[mf][j] += mskd ? 0.f : __expf(acc[mf][j]*0.125f);
      }
    }
  }
  #pragma unroll
  for (int off=1; off<16; off<<=1){
    #pragma unroll
    for (int mf=0;mf<4;++mf){
      #pragma unroll
      for (int j=0;j<4;++j) lacc[mf][j] += __shfl_xor(lacc[mf][j], off);
    }
  }
  if (r == 0){
    #pragma unroll
    for (int mf=0;mf<4;++mf){
      #pragma unroll
      for (int j=0;j<4;++j){
        int q = wv*64 + mf*16 + g*4 + j;
        lpart[(size_t)bid*256 + q] = lacc[mf][j];
      }
    }
  }
}

// ---------------- combine chunk sums -> inv l (0 for dead rows) ----------------
__global__ void lcomb_kernel(const float* __restrict__ lpart, float* __restrict__ linv){
  int row = blockIdx.x*256 + threadIdx.x;   // B*H*Q = 16384
  int q = row & 255, bh = row >> 8;
  float l = 0.f;
  #pragma unroll
  for (int sc=0; sc<16; ++sc) l += lpart[(size_t)(bh*16+sc)*256 + q];
  linv[row] = (l > 0.f) ? (1.0f/l) : 0.f;
}

// -------- phase2 (exact R12): SBLK=128, single-buffer, sQ LDS-staged; swapped QK^T; head-mean; bf16 O-partials --------
__global__ __launch_bounds__(512,4) void attn_pv_kernel(const short* __restrict__ qp, const short* __restrict__ kb,
                                                        const short* __restrict__ vt, const unsigned* __restrict__ pm,
                                                        const float* __restrict__ linv, short* __restrict__ opart,
                                                        float* __restrict__ out2){
  int bid = blockIdx.x;             // ((b*4+qt)*32 + sc)
  int sc = bid & 31, qt = (bid>>5)&3, b = bid>>7;
  int s0 = sc*128, q0 = qt*64;
  int half = sc & 1, scq = sc >> 1;
  __shared__ short sK[128*64];      // K tile; becomes P (64q x 128s) after QK^T
  __shared__ short sV[64*128];
  __shared__ short sQ[64*64];
  __shared__ unsigned sPM[64*4];
  int tid=threadIdx.x, lane=tid&63, wv=tid>>6, g=lane>>4, r=lane&15;
  int wq = wv>>2, ws = wv&3;
  f4v z = {0.f,0.f,0.f,0.f};
  float macc[2][2][4];              // [sb][qb][j]
  #pragma unroll
  for (int sb=0;sb<2;++sb){
    #pragma unroll
    for (int qb=0;qb<2;++qb){
      #pragma unroll
      for (int j=0;j<4;++j) macc[sb][qb][j] = 0.f;
    }
  }

  for (int h=0; h<16; ++h){
    int bh = b*16 + h;
    // ---- stage (single buffer) ----
    { int row = tid>>3, cbs = (tid&7)^(row&7);
      gload16(qp + (size_t)(b*256 + q0 + row)*1024 + h*64 + cbs*8, &sQ[(wv*64)*8]); }
    #pragma unroll
    for (int i=0;i<2;++i){
      int idx = i*512 + tid;
      int row = idx>>3, cbs = (idx&7)^(row&7);
      gload16(kb + (size_t)(b*4096 + s0 + row)*1024 + h*64 + cbs*8, &sK[(i*512+wv*64)*8]);
    }
    #pragma unroll
    for (int i=0;i<2;++i){
      int idx = i*512 + tid;
      int row = idx>>4, sl = idx&15, sls = sl^(row&7);
      gload16(vt + (size_t)(bh*64 + row)*4096 + s0 + sls*8, &sV[(i*512+wv*64)*8]);
    }
    if (tid < 256)
      sPM[tid] = pm[(size_t)(bh*16+scq)*2048 + (q0 + (tid>>2))*8 + (tid&3)*2 + half];
    __syncthreads();   // stage complete (drains vmcnt)

    // ---- QK^T swapped: acc[s][q] = mfma(K, Q) ----
    b8v qf[2][2];
    #pragma unroll
    for (int qb=0;qb<2;++qb){
      #pragma unroll
      for (int ks=0;ks<2;++ks){
        int qrow = wq*32 + qb*16 + r;
        qf[qb][ks] = ldsf(&sQ[qrow*64 + (((ks*4+g)^(qrow&7))*8)]);
      }
    }
    f4v accs[2][2];
    __builtin_amdgcn_s_setprio(1);
    #pragma unroll
    for (int sb=0;sb<2;++sb){
      int srow = ws*32 + sb*16 + r;
      b8v k0 = ldsf(&sK[srow*64 + ((g^(srow&7))*8)]);
      b8v k1 = ldsf(&sK[srow*64 + (((4+g)^(srow&7))*8)]);
      #pragma unroll
      for (int qb=0;qb<2;++qb){
        accs[sb][qb] = mfma16(k0, qf[qb][0], z);
        accs[sb][qb] = mfma16(k1, qf[qb][1], accs[sb][qb]);
      }
    }
    __builtin_amdgcn_s_setprio(0);
    lds_barrier();     // B1: sK/sQ reads done, safe to overlay P

    // ---- softmax; write P[q][s] into sK (b64 packed writes) ----
    float iv[2];
    iv[0] = linv[(size_t)bh*256 + q0 + wq*32 + r];
    iv[1] = linv[(size_t)bh*256 + q0 + wq*32 + 16 + r];
    unsigned wmq[2][4];
    #pragma unroll
    for (int qb=0;qb<2;++qb){
      #pragma unroll
      for (int j=0;j<4;++j)
        wmq[qb][j] = sPM[(wq*32+qb*16+r)*4 + j];
    }
    short* P = &sK[0];
    #pragma unroll
    for (int sb=0;sb<2;++sb){
      int bitp = ws*8 + sb*4 + g;
      #pragma unroll
      for (int qb=0;qb<2;++qb){
        float pj[4];
        #pragma unroll
        for (int j=0;j<4;++j){
          bool mskd = (wmq[qb][j] >> bitp) & 1u;
          pj[j] = mskd ? 0.f : __expf(accs[sb][qb][j]*0.125f) * iv[qb];
          macc[sb][qb][j] += pj[j];
        }
        int q = wq*32 + qb*16 + r;
        unsigned lo = ((unsigned)(unsigned short)f2b(pj[0])) | (((unsigned)(unsigned short)f2b(pj[1]))<<16);
        unsigned hi = ((unsigned)(unsigned short)f2b(pj[2])) | (((unsigned)(unsigned short)f2b(pj[3]))<<16);
        int sbase = (ws*32 + sb*16 + g*4) ^ ((q&7)<<3);
        uint2 pk; pk.x = lo; pk.y = hi;
        *(uint2*)&P[q*128 + sbase] = pk;
      }
    }
    lds_barrier();     // B2: P visible

    // ---- PV: O[q][d] += P[q][s] * V[s][d] (s over 128) ----
    f4v acco[2]; acco[0]=z; acco[1]=z;
    __builtin_amdgcn_s_setprio(1);
    #pragma unroll
    for (int ks=0;ks<4;++ks){
      int vrow = ws*16 + r;
      b8v bv = ldsf(&sV[vrow*128 + ((ks*32+g*8) ^ ((vrow&7)<<3))]);
      #pragma unroll
      for (int mf=0;mf<2;++mf){
        int prow = wq*32 + mf*16 + r;
        b8v ap = ldsf(&P[prow*128 + ((ks*32+g*8) ^ ((prow&7)<<3))]);
        acco[mf] = mfma16(ap, bv, acco[mf]);
      }
    }
    __builtin_amdgcn_s_setprio(0);
    #pragma unroll
    for (int mf=0;mf<2;++mf){
      #pragma unroll
      for (int j=0;j<4;++j)
        opart[((size_t)sc*1024 + b*256 + q0 + wq*32 + mf*16 + g*4 + j)*1024 + h*64 + ws*16 + r] = f2b(acco[mf][j]);
    }
    lds_barrier();     // B3: all LDS reads done before next head's stage overwrites
  }

  // ---- out2 = head-mean, coalesced float4 stores ----
  #pragma unroll
  for (int sb=0;sb<2;++sb){
    #pragma unroll
    for (int qb=0;qb<2;++qb){
      int q = q0 + wq*32 + qb*16 + r;
      float4 o = make_float4(macc[sb][qb][0]*0.0625f, macc[sb][qb][1]*0.0625f,
                             macc[sb][qb][2]*0.0625f, macc[sb][qb][3]*0.0625f);
      *(float4*)&out2[(size_t)(b*256 + q)*4096 + s0 + ws*32 + sb*16 + g*4] = o;
    }
  }
}

// ---------------- launcher ----------------
extern "C" void kernel_launch(void* const* d_in, const int* in_sizes, int n_in,
                              void* d_out, int out_size, void* d_ws, size_t ws_size,
                              hipStream_t stream){
  const float* x       = (const float*)d_in[0];
  const float* queries = (const float*)d_in[1];
  const int*   am      = (const int*)d_in[2];
  const int*   kpm     = (const int*)d_in[3];
  const float* Wq      = (const float*)d_in[4];
  const float* Wk      = (const float*)d_in[5];
  const float* Wv      = (const float*)d_in[6];
  const float* Wo      = (const float*)d_in[7];
  const float* ln1g    = (const float*)d_in[8];
  const float* ln1b    = (const float*)d_in[9];
  const float* ln2g    = (const float*)d_in[10];
  const float* ln2b    = (const float*)d_in[11];
  float* out0 = (float*)d_out;
  float* out2 = out0 + (size_t)4*256*1024;
  char* ws = (char*)d_ws;

  size_t off = 0;
  auto alloc = [&](size_t bytes){ void* p = ws + off; off += (bytes + 255) & ~(size_t)255; return p; };
  short*    xn   = (short*)alloc(33554432);   // (B*S, D) bf16
  short*    kb   = (short*)alloc(33554432);   // (B,S,D) bf16
  short*    vt   = (short*)alloc(33554432);   // (B,H,hd,S) bf16 — written directly by V GEMM
  short*    wqb  = (short*)alloc(2097152);
  short*    wkb  = (short*)alloc(2097152);
  short*    wvb  = (short*)alloc(2097152);
  short*    wob  = (short*)alloc(2097152);
  short*    qbf  = (short*)alloc(2097152);    // queries bf16
  short*    qpj  = (short*)alloc(2097152);    // projected q bf16
  unsigned* pmw  = (unsigned*)alloc(8388608); // packed mask bits, [bh*16+sc256][256 q][8 words]
  float*    lpart= (float*)alloc(1048576);    // per-chunk l sums [1024][256]
  float*    linv = (float*)alloc(65536);      // 1/l (or 0)
  short*    opart= (short*)alloc(67108864);   // O partials per s-chunk: [32][B*Q][1024] bf16
  short*    onb  = (short*)alloc(2097152);    // ln2 output bf16

  prep_kernel<<<21504,256,0,stream>>>(x, ln1g, ln1b, xn,
                                      queries, Wq, Wk, Wv, Wo, qbf, wqb, wkb, wvb, wob);
  gemm_dual8<<<dim3(64,8),512,0,stream>>>(xn, wkb, wvb, kb, vt);
  gemm_small<0><<<dim3(16,16),256,0,stream>>>(qbf, wqb, qpj, 1024, 1024, 1024);
  lsum_kernel<<<1024,256,0,stream>>>(qpj, kb, am, kpm, pmw, lpart);
  lcomb_kernel<<<64,256,0,stream>>>(lpart, linv);
  attn_pv_kernel<<<512,512,0,stream>>>(qpj, kb, vt, pmw, linv, opart, out2);
  ln_reduce_kernel<<<1024,256,0,stream>>>(opart, ln2g, ln2b, onb);
  gemm_small<1><<<dim3(16,16),256,0,stream>>>(onb, wob, out0, 1024, 1024, 1024);
}

// Round 15
// 316.110 us; speedup vs baseline: 1.1956x; 1.0027x over previous
//
#include <hip/hip_runtime.h>
#include <math.h>

#define DEV __device__ __forceinline__

typedef float  f4v  __attribute__((ext_vector_type(4)));
typedef __bf16 b8v  __attribute__((ext_vector_type(8)));
typedef short  s8v  __attribute__((ext_vector_type(8)));

DEV short f2b(float f){ __bf16 h = (__bf16)f; return __builtin_bit_cast(short, h); }
DEV float b2f(short s){ __bf16 h = __builtin_bit_cast(__bf16, s); return (float)h; }

DEV void gload16(const void* g, void* l){
  __builtin_amdgcn_global_load_lds((const __attribute__((address_space(1))) void*)g,
                                   (__attribute__((address_space(3))) void*)l, 16, 0, 0);
}

DEV b8v ldsf(const short* p){ return __builtin_bit_cast(b8v, *(const s8v*)p); }

DEV f4v mfma16(b8v a, b8v b, f4v c){ return __builtin_amdgcn_mfma_f32_16x16x32_bf16(a, b, c, 0, 0, 0); }

// LDS-only barrier: does NOT drain vmcnt (m201 pattern).
DEV void lds_barrier(){
  asm volatile("s_waitcnt lgkmcnt(0)" ::: "memory");
  __builtin_amdgcn_s_barrier();
}

// ---------------- prep: ln(x) -> xn  AND  f32->bf16 converts, one launch ----------------
__global__ __launch_bounds__(256) void prep_kernel(const float* __restrict__ x, const float* __restrict__ ln1g,
                                                   const float* __restrict__ ln1b, short* __restrict__ xn,
                                                   const float* __restrict__ s0, const float* __restrict__ s1,
                                                   const float* __restrict__ s2, const float* __restrict__ s3,
                                                   const float* __restrict__ s4,
                                                   short* __restrict__ d0, short* __restrict__ d1,
                                                   short* __restrict__ d2, short* __restrict__ d3,
                                                   short* __restrict__ d4){
  int bid = blockIdx.x, tid = threadIdx.x;
  if (bid < 5120){
    int i = bid*256 + tid;   // 5 * 262144 float4s
    int buf = i >> 18, j = i & 262143;
    const float* s = (buf==0)?s0:(buf==1)?s1:(buf==2)?s2:(buf==3)?s3:s4;
    short*       d = (buf==0)?d0:(buf==1)?d1:(buf==2)?d2:(buf==3)?d3:d4;
    float4 v = ((const float4*)s)[j];
    ((short4*)d)[j] = make_short4(f2b(v.x), f2b(v.y), f2b(v.z), f2b(v.w));
    return;
  }
  int row = bid - 5120;
  const float4 v = ((const float4*)(x + (size_t)row*1024))[tid];
  float s = v.x + v.y + v.z + v.w;
  #pragma unroll
  for (int off=1; off<64; off<<=1) s += __shfl_xor(s, off);
  __shared__ float red[4];
  if ((tid&63)==0) red[tid>>6] = s;
  __syncthreads();
  float mu = (red[0]+red[1]+red[2]+red[3]) * (1.0f/1024.0f);
  float e0=v.x-mu, e1=v.y-mu, e2=v.z-mu, e3=v.w-mu;
  float q = e0*e0 + e1*e1 + e2*e2 + e3*e3;
  #pragma unroll
  for (int off=1; off<64; off<<=1) q += __shfl_xor(q, off);
  __syncthreads();
  if ((tid&63)==0) red[tid>>6] = q;
  __syncthreads();
  float rs = rsqrtf((red[0]+red[1]+red[2]+red[3]) * (1.0f/1024.0f) + 1e-5f);
  float4 g4 = ((const float4*)ln1g)[tid];
  float4 b4 = ((const float4*)ln1b)[tid];
  short4 o = make_short4(f2b(e0*rs*g4.x + b4.x), f2b(e1*rs*g4.y + b4.y),
                         f2b(e2*rs*g4.z + b4.z), f2b(e3*rs*g4.w + b4.w));
  ((short4*)(xn + (size_t)row*1024))[tid] = o;
}

// ------- LayerNorm fused with 32-slice sum reduce, s8v loads, 2 rows/block -------
__global__ __launch_bounds__(256) void ln_reduce_kernel(const short* __restrict__ opart, const float* __restrict__ gg,
                                                        const float* __restrict__ bb, short* __restrict__ out){
  int tid = threadIdx.x;
  int row = blockIdx.x*2 + (tid>>7);
  int c8  = tid & 127;                  // cols c8*8 .. c8*8+7
  float a[8];
  #pragma unroll
  for (int k=0;k<8;++k) a[k] = 0.f;
  #pragma unroll
  for (int sc=0; sc<32; ++sc){
    s8v t = *(const s8v*)(opart + ((size_t)sc*1024 + row)*1024 + c8*8);
    #pragma unroll
    for (int k=0;k<8;++k) a[k] += b2f(t[k]);
  }
  float s = 0.f;
  #pragma unroll
  for (int k=0;k<8;++k) s += a[k];
  #pragma unroll
  for (int off=1; off<64; off<<=1) s += __shfl_xor(s, off);
  __shared__ float red[4];
  if ((tid&63)==0) red[tid>>6] = s;
  __syncthreads();
  int rb = (tid>>7)*2;                  // row0 -> red[0..1], row1 -> red[2..3]
  float mu = (red[rb]+red[rb+1]) * (1.0f/1024.0f);
  float d[8], q = 0.f;
  #pragma unroll
  for (int k=0;k<8;++k){ d[k] = a[k]-mu; q += d[k]*d[k]; }
  #pragma unroll
  for (int off=1; off<64; off<<=1) q += __shfl_xor(q, off);
  __syncthreads();
  if ((tid&63)==0) red[tid>>6] = q;
  __syncthreads();
  float rs = rsqrtf((red[rb]+red[rb+1]) * (1.0f/1024.0f) + 1e-5f);
  float4 g0 = ((const float4*)gg)[c8*2], g1 = ((const float4*)gg)[c8*2+1];
  float4 b0 = ((const float4*)bb)[c8*2], b1 = ((const float4*)bb)[c8*2+1];
  float gv[8] = {g0.x,g0.y,g0.z,g0.w,g1.x,g1.y,g1.z,g1.w};
  float bv[8] = {b0.x,b0.y,b0.z,b0.w,b1.x,b1.y,b1.z,b1.w};
  s8v o;
  #pragma unroll
  for (int k=0;k<8;++k) o[k] = f2b(d[k]*rs*gv[k] + bv[k]);
  *(s8v*)(out + (size_t)row*1024 + c8*8) = o;
}

// ---------------- small GEMM (M,N ~1024): 64x64 tile, BK=64, counted-vmcnt 2-phase ----------------
template<int OUTF32>
__global__ __launch_bounds__(256) void gemm_small(const short* __restrict__ A, const short* __restrict__ B,
                                                  void* __restrict__ C, int M, int N, int K){
  __shared__ short sA[2][64*64];
  __shared__ short sB[2][64*64];
  int tid=threadIdx.x, lane=tid&63, wv=tid>>6, g=lane>>4, r=lane&15;
  int wr=wv>>1, wc=wv&1;
  int m0=blockIdx.x*64, n0=blockIdx.y*64;
  f4v z = {0.f,0.f,0.f,0.f};
  f4v acc[2][2];
  #pragma unroll
  for (int i=0;i<2;++i){
    #pragma unroll
    for (int j=0;j<2;++j) acc[i][j]=z;
  }
  auto stage = [&](int buf, int kt){   // exactly 4 VMEM ops per thread
    #pragma unroll
    for (int i=0;i<2;++i){
      int idx = i*256 + tid;
      int row = idx>>3, cbs = (idx&7)^(row&7);
      gload16(A + (size_t)(m0+row)*K + kt*64 + cbs*8, &sA[buf][(i*256+wv*64)*8]);
      gload16(B + (size_t)(n0+row)*K + kt*64 + cbs*8, &sB[buf][(i*256+wv*64)*8]);
    }
  };
  int nkt = K >> 6;
  stage(0, 0);
  for (int kt=0; kt<nkt; ++kt){
    int cur = kt & 1;
    if (kt+1 < nkt){
      stage(cur^1, kt+1);
      asm volatile("s_waitcnt vmcnt(4)" ::: "memory");  // cur tile landed; prefetch in flight
    } else {
      asm volatile("s_waitcnt vmcnt(0)" ::: "memory");
    }
    __builtin_amdgcn_s_barrier();
    b8v af[2][2], bf[2][2];
    #pragma unroll
    for (int mf=0;mf<2;++mf){
      #pragma unroll
      for (int ks=0;ks<2;++ks){
        int ra = wr*32 + mf*16 + r;
        int rb = wc*32 + mf*16 + r;
        af[mf][ks] = ldsf(&sA[cur][ra*64 + (((ks*4+g)^(ra&7))*8)]);
        bf[mf][ks] = ldsf(&sB[cur][rb*64 + (((ks*4+g)^(rb&7))*8)]);
      }
    }
    #pragma unroll
    for (int mf=0;mf<2;++mf){
      #pragma unroll
      for (int nf=0;nf<2;++nf){
        acc[mf][nf] = mfma16(af[mf][0], bf[nf][0], acc[mf][nf]);
        acc[mf][nf] = mfma16(af[mf][1], bf[nf][1], acc[mf][nf]);
      }
    }
    asm volatile("s_waitcnt lgkmcnt(0)" ::: "memory");  // own LDS reads done
    __builtin_amdgcn_s_barrier();                       // everyone done -> safe to re-stage
  }
  #pragma unroll
  for (int mf=0;mf<2;++mf){
    #pragma unroll
    for (int nf=0;nf<2;++nf){
      #pragma unroll
      for (int j=0;j<4;++j){
        int m = m0 + wr*32 + mf*16 + g*4 + j;
        int n = n0 + wc*32 + nf*16 + r;
        if (OUTF32) ((float*)C)[(size_t)m*N + n] = acc[mf][nf][j];
        else        ((short*)C)[(size_t)m*N + n] = f2b(acc[mf][nf][j]);
      }
    }
  }
}

// ======== fused K+V 8-phase GEMM: BM=256, BN=128 per output, BK=64, counted vmcnt ========
__global__ __launch_bounds__(512,1) void gemm_dual8(const short* __restrict__ A, const short* __restrict__ B0,
                                                    const short* __restrict__ B1, short* __restrict__ C0,
                                                    short* __restrict__ vt){
  __shared__ short sA[2][256*64];   // 64 KB  (halves: rows 0-127 / 128-255 of lds-rows)
  __shared__ short sBK[2][128*64];  // 32 KB
  __shared__ short sBV[2][128*64];  // 32 KB
  int tid=threadIdx.x, lane=tid&63, wv=tid>>6, g=lane>>4, r=lane&15;
  int wr=wv>>2, wc=wv&3;            // 2M x 4N waves; wave tile 128m x 32n per output
  int m0 = blockIdx.x*256, n0 = blockIdx.y*128;
  f4v z = {0.f,0.f,0.f,0.f};
  f4v ac0[8][2], ac1[8][2];
  #pragma unroll
  for (int i=0;i<8;++i){
    #pragma unroll
    for (int j=0;j<2;++j){ ac0[i][j]=z; ac1[i][j]=z; }
  }
  auto stageA = [&](int buf, int kt, int h){
    #pragma unroll
    for (int ii=0; ii<2; ++ii){
      int idx = ii*512 + tid;                       // 0..1023 within half
      int rl = idx>>3, cs = (idx&7)^(rl&7);
      int rowA = (((rl>>6)&1)<<7) | (h<<6) | (rl&63);
      gload16(A + (size_t)(m0+rowA)*1024 + kt*64 + cs*8,
              &sA[buf][(h*1024 + ii*512 + wv*64)*8]);
    }
  };
  auto stageBK = [&](int buf, int kt){
    #pragma unroll
    for (int ii=0; ii<2; ++ii){
      int idx = ii*512 + tid;
      int rl = idx>>3, cs = (idx&7)^(rl&7);
      gload16(B0 + (size_t)(n0+rl)*1024 + kt*64 + cs*8, &sBK[buf][(ii*512+wv*64)*8]);
    }
  };
  auto stageBV = [&](int buf, int kt){
    #pragma unroll
    for (int ii=0; ii<2; ++ii){
      int idx = ii*512 + tid;
      int rl = idx>>3, cs = (idx&7)^(rl&7);
      gload16(B1 + (size_t)(n0+rl)*1024 + kt*64 + cs*8, &sBV[buf][(ii*512+wv*64)*8]);
    }
  };
  // prologue (tile 0), issue order matches in-loop absolute ordering
  stageA(0,0,0); stageBK(0,0); stageBV(0,0); stageA(0,0,1);

  b8v af[4][2], bk[2][2], bv[2][2];
  #pragma unroll 2
  for (int t=0; t<16; ++t){
    int cur = t&1, nxt = cur^1;
    // ---- phase 0: (A half0) x BK ----
    asm volatile("s_waitcnt vmcnt(4)" ::: "memory");
    __builtin_amdgcn_s_barrier();
    __builtin_amdgcn_sched_barrier(0);
    if (t < 15) stageA(nxt, t+1, 0);
    #pragma unroll
    for (int ml=0;ml<4;++ml){
      int lr = wr*64 + ml*16 + r;                   // half0
      #pragma unroll
      for (int ks=0;ks<2;++ks)
        af[ml][ks] = ldsf(&sA[cur][lr*64 + (((ks*4+g)^(r&7))*8)]);
    }
    #pragma unroll
    for (int nf=0;nf<2;++nf){
      int lr = wc*32 + nf*16 + r;
      #pragma unroll
      for (int ks=0;ks<2;++ks)
        bk[nf][ks] = ldsf(&sBK[cur][lr*64 + (((ks*4+g)^(r&7))*8)]);
    }
    __builtin_amdgcn_s_setprio(1);
    #pragma unroll
    for (int ml=0;ml<4;++ml){
      #pragma unroll
      for (int nf=0;nf<2;++nf){
        ac0[ml][nf] = mfma16(af[ml][0], bk[nf][0], ac0[ml][nf]);
        ac0[ml][nf] = mfma16(af[ml][1], bk[nf][1], ac0[ml][nf]);
      }
    }
    __builtin_amdgcn_s_setprio(0);
    // ---- phase 1: (A half0) x BV ----
    if (t < 15) { asm volatile("s_waitcnt vmcnt(4)" ::: "memory"); }
    else        { asm volatile("s_waitcnt vmcnt(2)" ::: "memory"); }
    __builtin_amdgcn_s_barrier();
    __builtin_amdgcn_sched_barrier(0);
    if (t < 15) stageBK(nxt, t+1);
    #pragma unroll
    for (int nf=0;nf<2;++nf){
      int lr = wc*32 + nf*16 + r;
      #pragma unroll
      for (int ks=0;ks<2;++ks)
        bv[nf][ks] = ldsf(&sBV[cur][lr*64 + (((ks*4+g)^(r&7))*8)]);
    }
    __builtin_amdgcn_s_setprio(1);
    #pragma unroll
    for (int ml=0;ml<4;++ml){
      #pragma unroll
      for (int nf=0;nf<2;++nf){
        ac1[ml][nf] = mfma16(af[ml][0], bv[nf][0], ac1[ml][nf]);
        ac1[ml][nf] = mfma16(af[ml][1], bv[nf][1], ac1[ml][nf]);
      }
    }
    __builtin_amdgcn_s_setprio(0);
    // ---- phase 2: (A half1) x BK ----
    if (t < 15) { asm volatile("s_waitcnt vmcnt(4)" ::: "memory"); }
    else        { asm volatile("s_waitcnt vmcnt(0)" ::: "memory"); }
    __builtin_amdgcn_s_barrier();
    __builtin_amdgcn_sched_barrier(0);
    if (t < 15) stageBV(nxt, t+1);
    #pragma unroll
    for (int ml=0;ml<4;++ml){
      int lr = 128 + wr*64 + ml*16 + r;             // half1
      #pragma unroll
      for (int ks=0;ks<2;++ks)
        af[ml][ks] = ldsf(&sA[cur][lr*64 + (((ks*4+g)^(r&7))*8)]);
    }
    __builtin_amdgcn_s_setprio(1);
    #pragma unroll
    for (int ml=0;ml<4;++ml){
      #pragma unroll
      for (int nf=0;nf<2;++nf){
        ac0[4+ml][nf] = mfma16(af[ml][0], bk[nf][0], ac0[4+ml][nf]);
        ac0[4+ml][nf] = mfma16(af[ml][1], bk[nf][1], ac0[4+ml][nf]);
      }
    }
    __builtin_amdgcn_s_setprio(0);
    // ---- phase 3: (A half1) x BV; no new LDS reads, no barrier ----
    if (t < 15) stageA(nxt, t+1, 1);
    __builtin_amdgcn_s_setprio(1);
    #pragma unroll
    for (int ml=0;ml<4;++ml){
      #pragma unroll
      for (int nf=0;nf<2;++nf){
        ac1[4+ml][nf] = mfma16(af[ml][0], bv[nf][0], ac1[4+ml][nf]);
        ac1[4+ml][nf] = mfma16(af[ml][1], bv[nf][1], ac1[4+ml][nf]);
      }
    }
    __builtin_amdgcn_s_setprio(0);
  }

  int b = m0 >> 12;
  #pragma unroll
  for (int mh=0; mh<2; ++mh){
    #pragma unroll
    for (int ml=0; ml<4; ++ml){
      #pragma unroll
      for (int nf=0; nf<2; ++nf){
        int m = m0 + wr*128 + mh*64 + ml*16 + g*4;
        int n = n0 + wc*32 + nf*16 + r;
        f4v a = ac0[mh*4+ml][nf];
        #pragma unroll
        for (int j=0;j<4;++j)
          C0[(size_t)(m+j)*1024 + n] = f2b(a[j]);
        f4v vvv = ac1[mh*4+ml][nf];
        int h = n >> 6, hd = n & 63;
        short4 vv = make_short4(f2b(vvv[0]), f2b(vvv[1]), f2b(vvv[2]), f2b(vvv[3]));
        *(short4*)&vt[(size_t)((b*16 + h)*64 + hd)*4096 + (m & 4095)] = vv;
      }
    }
  }
}

// ---------------- l-pass: ballot mask pack + l = sum(exp(s/8)) over unmasked ----------------
// pm word layout per (q-row): word w = (s&3)*2 + (s>>7), bit = (s>>2)&31
__global__ __launch_bounds__(256,2) void lsum_kernel(const short* __restrict__ qp, const short* __restrict__ kb,
                                                     const int* __restrict__ am, const int* __restrict__ kpm,
                                                     unsigned* __restrict__ pm, float* __restrict__ lpart){
  int bid = blockIdx.x;             // bh*16 + sc
  int sc = bid & 15, bh = bid >> 4;
  int b = bh >> 4, h = bh & 15;
  int s0 = sc*256;
  __shared__ short sQ[256*64];
  __shared__ short sK[256*64];
  __shared__ unsigned sPM[256*8];
  int tid=threadIdx.x, lane=tid&63, wv=tid>>6, g=lane>>4, r=lane&15;

  #pragma unroll
  for (int i=0;i<8;++i){
    int idx = i*256 + wv*64 + lane;
    int row = idx>>3, cbs = (idx&7)^(row&7);
    gload16(qp + (size_t)(b*256 + row)*1024 + h*64 + cbs*8, &sQ[(i*256+wv*64)*8]);
  }
  #pragma unroll
  for (int i=0;i<8;++i){
    int idx = i*256 + wv*64 + lane;
    int row = idx>>3, cbs = (idx&7)^(row&7);
    gload16(kb + (size_t)(b*4096 + s0 + row)*1024 + h*64 + cbs*8, &sK[(i*256+wv*64)*8]);
  }
  // key-padding row, lane l covers s = 4l..4l+3
  int4 kp = *(const int4*)(kpm + (size_t)b*4096 + s0 + lane*4);
  bool k0 = kp.x!=0, k1 = kp.y!=0, k2 = kp.z!=0, k3 = kp.w!=0;
  // wave-coalesced mask rows: 64 rows per wave
  #pragma unroll 4
  for (int i=0;i<64;++i){
    int row = wv*64 + i;
    const int4 t = *(const int4*)(am + (size_t)(bh*256 + row)*4096 + s0 + lane*4);
    unsigned long long m0 = __ballot(k0 || (t.x!=0));
    unsigned long long m1 = __ballot(k1 || (t.y!=0));
    unsigned long long m2 = __ballot(k2 || (t.z!=0));
    unsigned long long m3 = __ballot(k3 || (t.w!=0));
    if (lane < 8){
      int jj = lane>>1, hh = lane&1;
      unsigned long long bj = (jj==0)?m0:((jj==1)?m1:((jj==2)?m2:m3));
      unsigned w = (unsigned)(bj >> (hh*32));
      sPM[row*8 + lane] = w;
      pm[(size_t)bid*2048 + row*8 + lane] = w;
    }
  }
  __syncthreads();

  b8v a[4][2];
  #pragma unroll
  for (int mf=0;mf<4;++mf){
    #pragma unroll
    for (int ks=0;ks<2;++ks){
      int q = wv*64 + mf*16 + r;
      a[mf][ks] = ldsf(&sQ[q*64 + (((ks*4+g)^(q&7))*8)]);
    }
  }
  unsigned wmr[4][4][2];
  #pragma unroll
  for (int mf=0;mf<4;++mf){
    #pragma unroll
    for (int jq=0;jq<4;++jq){
      int q = wv*64 + mf*16 + g*4 + jq;
      wmr[mf][jq][0] = sPM[q*8 + (r&3)*2 + 0];
      wmr[mf][jq][1] = sPM[q*8 + (r&3)*2 + 1];
    }
  }
  float lacc[4][4];
  #pragma unroll
  for (int mf=0;mf<4;++mf){
    #pragma unroll
    for (int j=0;j<4;++j) lacc[mf][j] = 0.f;
  }
  f4v z = {0.f,0.f,0.f,0.f};
  #pragma unroll 4
  for (int nf=0;nf<16;++nf){
    int srow = nf*16 + r;
    b8v b0 = ldsf(&sK[srow*64 + ((g^(srow&7))*8)]);
    b8v b1 = ldsf(&sK[srow*64 + (((4+g)^(srow&7))*8)]);
    f4v acc[4];
    #pragma unroll
    for (int mf=0;mf<4;++mf){
      acc[mf] = mfma16(a[mf][0], b0, z);
      acc[mf] = mfma16(a[mf][1], b1, acc[mf]);
    }
    int bitp = 4*(nf&7) + (r>>2);
    #pragma unroll
    for (int mf=0;mf<4;++mf){
      #pragma unroll
      for (int j=0;j<4;++j){
        bool mskd = (wmr[mf][j][nf>>3] >> bitp) & 1u;
        lacc[mf][j] += mskd ? 0.f : __expf(acc[mf][j]*0.125f);
      }
    }
  }
  #pragma unroll
  for (int off=1; off<16; off<<=1){
    #pragma unroll
    for (int mf=0;mf<4;++mf){
      #pragma unroll
      for (int j=0;j<4;++j) lacc[mf][j] += __shfl_xor(lacc[mf][j], off);
    }
  }
  if (r == 0){
    #pragma unroll
    for (int mf=0;mf<4;++mf){
      #pragma unroll
      for (int j=0;j<4;++j){
        int q = wv*64 + mf*16 + g*4 + j;
        lpart[(size_t)bid*256 + q] = lacc[mf][j];
      }
    }
  }
}

// ---------------- combine chunk sums -> inv l (0 for dead rows) ----------------
__global__ void lcomb_kernel(const float* __restrict__ lpart, float* __restrict__ linv){
  int row = blockIdx.x*256 + threadIdx.x;   // B*H*Q = 16384
  int q = row & 255, bh = row >> 8;
  float l = 0.f;
  #pragma unroll
  for (int sc=0; sc<16; ++sc) l += lpart[(size_t)(bh*16+sc)*256 + q];
  linv[row] = (l > 0.f) ? (1.0f/l) : 0.f;
}

// -------- phase2 (exact R12): SBLK=128, single-buffer, sQ LDS-staged; swapped QK^T; head-mean; bf16 O-partials --------
__global__ __launch_bounds__(512,4) void attn_pv_kernel(const short* __restrict__ qp, const short* __restrict__ kb,
                                                        const short* __restrict__ vt, const unsigned* __restrict__ pm,
                                                        const float* __restrict__ linv, short* __restrict__ opart,
                                                        float* __restrict__ out2){
  int bid = blockIdx.x;             // ((b*4+qt)*32 + sc)
  int sc = bid & 31, qt = (bid>>5)&3, b = bid>>7;
  int s0 = sc*128, q0 = qt*64;
  int half = sc & 1, scq = sc >> 1;
  __shared__ short sK[128*64];      // K tile; becomes P (64q x 128s) after QK^T
  __shared__ short sV[64*128];
  __shared__ short sQ[64*64];
  __shared__ unsigned sPM[64*4];
  int tid=threadIdx.x, lane=tid&63, wv=tid>>6, g=lane>>4, r=lane&15;
  int wq = wv>>2, ws = wv&3;
  f4v z = {0.f,0.f,0.f,0.f};
  float macc[2][2][4];              // [sb][qb][j]
  #pragma unroll
  for (int sb=0;sb<2;++sb){
    #pragma unroll
    for (int qb=0;qb<2;++qb){
      #pragma unroll
      for (int j=0;j<4;++j) macc[sb][qb][j] = 0.f;
    }
  }

  for (int h=0; h<16; ++h){
    int bh = b*16 + h;
    // ---- stage (single buffer) ----
    { int row = tid>>3, cbs = (tid&7)^(row&7);
      gload16(qp + (size_t)(b*256 + q0 + row)*1024 + h*64 + cbs*8, &sQ[(wv*64)*8]); }
    #pragma unroll
    for (int i=0;i<2;++i){
      int idx = i*512 + tid;
      int row = idx>>3, cbs = (idx&7)^(row&7);
      gload16(kb + (size_t)(b*4096 + s0 + row)*1024 + h*64 + cbs*8, &sK[(i*512+wv*64)*8]);
    }
    #pragma unroll
    for (int i=0;i<2;++i){
      int idx = i*512 + tid;
      int row = idx>>4, sl = idx&15, sls = sl^(row&7);
      gload16(vt + (size_t)(bh*64 + row)*4096 + s0 + sls*8, &sV[(i*512+wv*64)*8]);
    }
    if (tid < 256)
      sPM[tid] = pm[(size_t)(bh*16+scq)*2048 + (q0 + (tid>>2))*8 + (tid&3)*2 + half];
    __syncthreads();   // stage complete (drains vmcnt)

    // ---- QK^T swapped: acc[s][q] = mfma(K, Q) ----
    b8v qf[2][2];
    #pragma unroll
    for (int qb=0;qb<2;++qb){
      #pragma unroll
      for (int ks=0;ks<2;++ks){
        int qrow = wq*32 + qb*16 + r;
        qf[qb][ks] = ldsf(&sQ[qrow*64 + (((ks*4+g)^(qrow&7))*8)]);
      }
    }
    f4v accs[2][2];
    __builtin_amdgcn_s_setprio(1);
    #pragma unroll
    for (int sb=0;sb<2;++sb){
      int srow = ws*32 + sb*16 + r;
      b8v k0 = ldsf(&sK[srow*64 + ((g^(srow&7))*8)]);
      b8v k1 = ldsf(&sK[srow*64 + (((4+g)^(srow&7))*8)]);
      #pragma unroll
      for (int qb=0;qb<2;++qb){
        accs[sb][qb] = mfma16(k0, qf[qb][0], z);
        accs[sb][qb] = mfma16(k1, qf[qb][1], accs[sb][qb]);
      }
    }
    __builtin_amdgcn_s_setprio(0);
    lds_barrier();     // B1: sK/sQ reads done, safe to overlay P

    // ---- softmax; write P[q][s] into sK (b64 packed writes) ----
    float iv[2];
    iv[0] = linv[(size_t)bh*256 + q0 + wq*32 + r];
    iv[1] = linv[(size_t)bh*256 + q0 + wq*32 + 16 + r];
    unsigned wmq[2][4];
    #pragma unroll
    for (int qb=0;qb<2;++qb){
      #pragma unroll
      for (int j=0;j<4;++j)
        wmq[qb][j] = sPM[(wq*32+qb*16+r)*4 + j];
    }
    short* P = &sK[0];
    #pragma unroll
    for (int sb=0;sb<2;++sb){
      int bitp = ws*8 + sb*4 + g;
      #pragma unroll
      for (int qb=0;qb<2;++qb){
        float pj[4];
        #pragma unroll
        for (int j=0;j<4;++j){
          bool mskd = (wmq[qb][j] >> bitp) & 1u;
          pj[j] = mskd ? 0.f : __expf(accs[sb][qb][j]*0.125f) * iv[qb];
          macc[sb][qb][j] += pj[j];
        }
        int q = wq*32 + qb*16 + r;
        unsigned lo = ((unsigned)(unsigned short)f2b(pj[0])) | (((unsigned)(unsigned short)f2b(pj[1]))<<16);
        unsigned hi = ((unsigned)(unsigned short)f2b(pj[2])) | (((unsigned)(unsigned short)f2b(pj[3]))<<16);
        int sbase = (ws*32 + sb*16 + g*4) ^ ((q&7)<<3);
        uint2 pk; pk.x = lo; pk.y = hi;
        *(uint2*)&P[q*128 + sbase] = pk;
      }
    }
    lds_barrier();     // B2: P visible

    // ---- PV: O[q][d] += P[q][s] * V[s][d] (s over 128) ----
    f4v acco[2]; acco[0]=z; acco[1]=z;
    __builtin_amdgcn_s_setprio(1);
    #pragma unroll
    for (int ks=0;ks<4;++ks){
      int vrow = ws*16 + r;
      b8v bv = ldsf(&sV[vrow*128 + ((ks*32+g*8) ^ ((vrow&7)<<3))]);
      #pragma unroll
      for (int mf=0;mf<2;++mf){
        int prow = wq*32 + mf*16 + r;
        b8v ap = ldsf(&P[prow*128 + ((ks*32+g*8) ^ ((prow&7)<<3))]);
        acco[mf] = mfma16(ap, bv, acco[mf]);
      }
    }
    __builtin_amdgcn_s_setprio(0);
    #pragma unroll
    for (int mf=0;mf<2;++mf){
      #pragma unroll
      for (int j=0;j<4;++j)
        opart[((size_t)sc*1024 + b*256 + q0 + wq*32 + mf*16 + g*4 + j)*1024 + h*64 + ws*16 + r] = f2b(acco[mf][j]);
    }
    lds_barrier();     // B3: all LDS reads done before next head's stage overwrites
  }

  // ---- out2 = head-mean, coalesced float4 stores ----
  #pragma unroll
  for (int sb=0;sb<2;++sb){
    #pragma unroll
    for (int qb=0;qb<2;++qb){
      int q = q0 + wq*32 + qb*16 + r;
      float4 o = make_float4(macc[sb][qb][0]*0.0625f, macc[sb][qb][1]*0.0625f,
                             macc[sb][qb][2]*0.0625f, macc[sb][qb][3]*0.0625f);
      *(float4*)&out2[(size_t)(b*256 + q)*4096 + s0 + ws*32 + sb*16 + g*4] = o;
    }
  }
}

// ---------------- launcher ----------------
extern "C" void kernel_launch(void* const* d_in, const int* in_sizes, int n_in,
                              void* d_out, int out_size, void* d_ws, size_t ws_size,
                              hipStream_t stream){
  const float* x       = (const float*)d_in[0];
  const float* queries = (const float*)d_in[1];
  const int*   am      = (const int*)d_in[2];
  const int*   kpm     = (const int*)d_in[3];
  const float* Wq      = (const float*)d_in[4];
  const float* Wk      = (const float*)d_in[5];
  const float* Wv      = (const float*)d_in[6];
  const float* Wo      = (const float*)d_in[7];
  const float* ln1g    = (const float*)d_in[8];
  const float* ln1b    = (const float*)d_in[9];
  const float* ln2g    = (const float*)d_in[10];
  const float* ln2b    = (const float*)d_in[11];
  float* out0 = (float*)d_out;
  float* out2 = out0 + (size_t)4*256*1024;
  char* ws = (char*)d_ws;

  size_t off = 0;
  auto alloc = [&](size_t bytes){ void* p = ws + off; off += (bytes + 255) & ~(size_t)255; return p; };
  short*    xn   = (short*)alloc(33554432);   // (B*S, D) bf16
  short*    kb   = (short*)alloc(33554432);   // (B,S,D) bf16
  short*    vt   = (short*)alloc(33554432);   // (B,H,hd,S) bf16 — written directly by V GEMM
  short*    wqb  = (short*)alloc(2097152);
  short*    wkb  = (short*)alloc(2097152);
  short*    wvb  = (short*)alloc(2097152);
  short*    wob  = (short*)alloc(2097152);
  short*    qbf  = (short*)alloc(2097152);    // queries bf16
  short*    qpj  = (short*)alloc(2097152);    // projected q bf16
  unsigned* pmw  = (unsigned*)alloc(8388608); // packed mask bits, [bh*16+sc256][256 q][8 words]
  float*    lpart= (float*)alloc(1048576);    // per-chunk l sums [1024][256]
  float*    linv = (float*)alloc(65536);      // 1/l (or 0)
  short*    opart= (short*)alloc(67108864);   // O partials per s-chunk: [32][B*Q][1024] bf16
  short*    onb  = (short*)alloc(2097152);    // ln2 output bf16

  prep_kernel<<<21504,256,0,stream>>>(x, ln1g, ln1b, xn,
                                      queries, Wq, Wk, Wv, Wo, qbf, wqb, wkb, wvb, wob);
  gemm_dual8<<<dim3(64,8),512,0,stream>>>(xn, wkb, wvb, kb, vt);
  gemm_small<0><<<dim3(16,16),256,0,stream>>>(qbf, wqb, qpj, 1024, 1024, 1024);
  lsum_kernel<<<1024,256,0,stream>>>(qpj, kb, am, kpm, pmw, lpart);
  lcomb_kernel<<<64,256,0,stream>>>(lpart, linv);
  attn_pv_kernel<<<512,512,0,stream>>>(qpj, kb, vt, pmw, linv, opart, out2);
  ln_reduce_kernel<<<512,256,0,stream>>>(opart, ln2g, ln2b, onb);
  gemm_small<1><<<dim3(16,16),256,0,stream>>>(onb, wob, out0, 1024, 1024, 1024);
}